// Round 4
// baseline (471.821 us; speedup 1.0000x reference)
//
#include <hip/hip_runtime.h>
#include <math.h>

#define N_NODES 50000
#define N_EDGES 800000
#define D_IN    128
#define D_H     32
#define N_HEADS 8
#define N_GRAPHS 512
#define E_TOT   (N_EDGES + N_NODES)      // 850000 (with self-loops)
#define HDIM    (N_HEADS * D_H)          // 256
#define NEG_SLOPE 0.2f
#define NSCAN_BLK ((N_NODES + 255) / 256)   // 196
#define RESCALE_THR 8.0f

typedef short bfrag8 __attribute__((ext_vector_type(8)));   // 8 bf16 = 4 VGPRs
typedef float f32x4 __attribute__((ext_vector_type(4)));

// ---- bf16 helpers ----
__device__ __forceinline__ float b2f(unsigned short u) {
    return __uint_as_float(((unsigned)u) << 16);
}
__device__ __forceinline__ unsigned short f2b(float x) {
    unsigned u = __float_as_uint(x);
    unsigned r = u + 0x7FFFu + ((u >> 16) & 1u);   // round-to-nearest-even
    return (unsigned short)(r >> 16);
}
__device__ __forceinline__ float4 u4f(ushort4 u) {
    float4 f;
    f.x = b2f(u.x); f.y = b2f(u.y); f.z = b2f(u.z); f.w = b2f(u.w);
    return f;
}

// ---- fused: edge-weight sum (fill value) + destination histogram ----
__global__ void k_hist_sum(const int* __restrict__ ei, const float* __restrict__ ew,
                           int* __restrict__ deg, float* __restrict__ fillsum) {
    int e = blockIdx.x * blockDim.x + threadIdx.x;
    float s = 0.f;
    if (e < E_TOT) {
        int dst = (e < N_EDGES) ? ei[N_EDGES + e] : (e - N_EDGES);
        atomicAdd(&deg[dst], 1);
        if (e < N_EDGES) s = ew[e];
    }
    for (int m = 1; m < 64; m <<= 1) s += __shfl_xor(s, m);
    if ((threadIdx.x & 63) == 0 && s != 0.f) atomicAdd(fillsum, s);
}

// ---- CSR scan (exclusive) ----
__global__ void k_scan1(const int* __restrict__ deg, int* __restrict__ start,
                        int* __restrict__ bsum) {
    __shared__ int sh[256];
    int i = blockIdx.x * 256 + threadIdx.x;
    int v = (i < N_NODES) ? deg[i] : 0;
    sh[threadIdx.x] = v;
    __syncthreads();
    for (int o = 1; o < 256; o <<= 1) {
        int t = (threadIdx.x >= o) ? sh[threadIdx.x - o] : 0;
        __syncthreads();
        sh[threadIdx.x] += t;
        __syncthreads();
    }
    if (i < N_NODES) start[i] = sh[threadIdx.x] - v;
    if (threadIdx.x == 255) bsum[blockIdx.x] = sh[255];
}
__global__ void k_scan2(int* __restrict__ bsum, int nb) {
    __shared__ int sh[256];
    int v = (threadIdx.x < nb) ? bsum[threadIdx.x] : 0;
    sh[threadIdx.x] = v;
    __syncthreads();
    for (int o = 1; o < 256; o <<= 1) {
        int t = (threadIdx.x >= o) ? sh[threadIdx.x - o] : 0;
        __syncthreads();
        sh[threadIdx.x] += t;
        __syncthreads();
    }
    if (threadIdx.x < nb) bsum[threadIdx.x] = sh[threadIdx.x] - v;
}
__global__ void k_scan3(int* __restrict__ start, const int* __restrict__ bsum) {
    int i = blockIdx.x * 256 + threadIdx.x;
    if (i < N_NODES) start[i] += bsum[blockIdx.x];
}

// ---- CSR scatter: packed (src, w) int2 ----
__global__ void k_scatter(const int* __restrict__ ei, const float* __restrict__ ew,
                          const float* __restrict__ fillsum,
                          const int* __restrict__ start, int* __restrict__ cur,
                          int2* __restrict__ csr) {
    int e = blockIdx.x * blockDim.x + threadIdx.x;
    if (e >= E_TOT) return;
    int src, dst; float w;
    if (e < N_EDGES) { src = ei[e]; dst = ei[N_EDGES + e]; w = ew[e]; }
    else { src = dst = e - N_EDGES; w = fillsum[0] * (1.0f / N_EDGES); }
    int pos = start[dst] + atomicAdd(&cur[dst], 1);
    csr[pos] = make_int2(src, __float_as_int(w));
}

// ---- fused prep: cast x to bf16 + build transposed bf16 weight panels ----
#define NC4      (N_NODES * D_IN / 4)        // 1,600,000 ushort4 casts
#define CAST_BLK ((NC4 + 255) / 256)         // 6250
#define W1_BLK   (512 * 128 / 256)           // 256
#define W2_BLK   (64 * 256 / 256)            // 64
__global__ void k_prep(const float* __restrict__ x,
                       const float* __restrict__ Wl1, const float* __restrict__ Wr1,
                       const float* __restrict__ Wl2, const float* __restrict__ Wr2,
                       unsigned short* __restrict__ xb,
                       unsigned short* __restrict__ Wt1,
                       unsigned short* __restrict__ Wt2) {
    int b = blockIdx.x;
    if (b < CAST_BLK) {
        int t = b * 256 + threadIdx.x;
        if (t >= NC4) return;
        float4 v = ((const float4*)x)[t];
        ushort4 o;
        o.x = f2b(v.x); o.y = f2b(v.y); o.z = f2b(v.z); o.w = f2b(v.w);
        ((ushort4*)xb)[t] = o;
    } else if (b < CAST_BLK + W1_BLK) {
        int t = (b - CAST_BLK) * 256 + threadIdx.x;   // t = c*128 + k
        int c = t >> 7, k = t & 127;
        float v = (c < 256) ? Wl1[k * 256 + c] : Wr1[k * 256 + (c - 256)];
        Wt1[t] = f2b(v);
    } else {
        int t = (b - CAST_BLK - W1_BLK) * 256 + threadIdx.x;   // t = c*256 + k
        int c = t >> 8, k = t & 255;
        float v = (c < 32) ? Wl2[k * 32 + c] : Wr2[k * 32 + (c - 32)];
        Wt2[t] = f2b(v);
    }
}

// ---- bf16 MFMA GEMM: C[M,N] = A[M,KC] * Bt[N,KC]^T, all bf16 row-major ----
template <int KC>
__global__ __launch_bounds__(256) void k_gemm_bf16(
    const unsigned short* __restrict__ A, const unsigned short* __restrict__ Bt,
    unsigned short* __restrict__ C, int M, int N)
{
    __shared__ unsigned short A_lds[64][KC + 8];
    __shared__ unsigned short B_lds[64][KC + 8];
    int row0 = blockIdx.y * 64, col0 = blockIdx.x * 64;
    int tid = threadIdx.x;
    const int CPR = KC / 8;
    for (int idx = tid; idx < 64 * CPR; idx += 256) {
        int r = idx / CPR, ch = idx % CPR;
        int gr = row0 + r;
        uint4 v = {0u, 0u, 0u, 0u};
        if (gr < M) v = *(const uint4*)(A + (size_t)gr * KC + ch * 8);
        *(uint4*)&A_lds[r][ch * 8] = v;
    }
    for (int idx = tid; idx < 64 * CPR; idx += 256) {
        int r = idx / CPR, ch = idx % CPR;
        uint4 v = *(const uint4*)(Bt + (size_t)(col0 + r) * KC + ch * 8);
        *(uint4*)&B_lds[r][ch * 8] = v;
    }
    __syncthreads();

    int wid = tid >> 6, lane = tid & 63;
    int wy = wid >> 1, wx = wid & 1;
    int lr = lane & 15, lh = lane >> 4;
    f32x4 acc[2][2] = {};
    #pragma unroll
    for (int k0 = 0; k0 < KC; k0 += 32) {
        bfrag8 a0 = *(const bfrag8*)&A_lds[32 * wy + lr][k0 + lh * 8];
        bfrag8 a1 = *(const bfrag8*)&A_lds[32 * wy + 16 + lr][k0 + lh * 8];
        bfrag8 b0 = *(const bfrag8*)&B_lds[32 * wx + lr][k0 + lh * 8];
        bfrag8 b1 = *(const bfrag8*)&B_lds[32 * wx + 16 + lr][k0 + lh * 8];
        acc[0][0] = __builtin_amdgcn_mfma_f32_16x16x32_bf16(a0, b0, acc[0][0], 0, 0, 0);
        acc[0][1] = __builtin_amdgcn_mfma_f32_16x16x32_bf16(a0, b1, acc[0][1], 0, 0, 0);
        acc[1][0] = __builtin_amdgcn_mfma_f32_16x16x32_bf16(a1, b0, acc[1][0], 0, 0, 0);
        acc[1][1] = __builtin_amdgcn_mfma_f32_16x16x32_bf16(a1, b1, acc[1][1], 0, 0, 0);
    }
    #pragma unroll
    for (int mt = 0; mt < 2; ++mt) {
        #pragma unroll
        for (int nt = 0; nt < 2; ++nt) {
            #pragma unroll
            for (int r = 0; r < 4; ++r) {
                int row = row0 + 32 * wy + 16 * mt + lh * 4 + r;
                if (row < M)
                    C[(size_t)row * N + col0 + 32 * wx + 16 * nt + lr] = f2b(acc[mt][nt][r]);
            }
        }
    }
}

// ---- fused layer-1: one wave per node; lane owns 4 of 256 channels ----
// xlr: [N][512] bf16 (cols 0..255 = xl, 256..511 = xr). 2-edge unroll +
// deferred-rescale online softmax. out1: [N][256] bf16.
__global__ __launch_bounds__(256) void k_gat1(
    const unsigned short* __restrict__ xlr,
    const int* __restrict__ start, const int* __restrict__ deg,
    const int2* __restrict__ csr,
    const float* __restrict__ We, const float* __restrict__ att,
    const float* __restrict__ b1, unsigned short* __restrict__ out1)
{
    int wid = (blockIdx.x * blockDim.x + threadIdx.x) >> 6;
    int lane = threadIdx.x & 63;
    if (wid >= N_NODES) return;
    float4 we4 = ((const float4*)We)[lane];
    float4 at4 = ((const float4*)att)[lane];
    float4 xr4 = u4f(*(const ushort4*)(xlr + (size_t)wid * 512 + 256 + 4 * lane));
    int s0 = start[wid], dg = deg[wid];
    const int2* ep = csr + s0;
    float m = -1e30f, d = 0.f;
    float4 acc = {0.f, 0.f, 0.f, 0.f};

    int2 ec0 = ep[0];
    int2 ec1 = ep[dg > 1 ? 1 : 0];
    ushort4 ra0 = *(const ushort4*)(xlr + ((size_t)ec0.x << 9) + 4 * lane);
    ushort4 ra1 = *(const ushort4*)(xlr + ((size_t)ec1.x << 9) + 4 * lane);

    for (int j = 0; j < dg; j += 2) {
        int2 c0 = ec0, c1 = ec1;
        ushort4 A0 = ra0, A1 = ra1;
        int jn = j + 2;
        if (jn < dg) {
            ec0 = ep[jn];
            ec1 = ep[(jn + 1 < dg) ? jn + 1 : jn];
            ra0 = *(const ushort4*)(xlr + ((size_t)ec0.x << 9) + 4 * lane);
            ra1 = *(const ushort4*)(xlr + ((size_t)ec1.x << 9) + 4 * lane);
        }
        float w0 = __int_as_float(c0.y), w1 = __int_as_float(c1.y);
        float4 a0 = u4f(A0), a1 = u4f(A1);
        float p0 = 0.f, p1 = 0.f, z, lz;
        z = a0.x + fmaf(w0, we4.x, xr4.x); lz = fmaxf(z, NEG_SLOPE * z); p0 = fmaf(lz, at4.x, p0);
        z = a0.y + fmaf(w0, we4.y, xr4.y); lz = fmaxf(z, NEG_SLOPE * z); p0 = fmaf(lz, at4.y, p0);
        z = a0.z + fmaf(w0, we4.z, xr4.z); lz = fmaxf(z, NEG_SLOPE * z); p0 = fmaf(lz, at4.z, p0);
        z = a0.w + fmaf(w0, we4.w, xr4.w); lz = fmaxf(z, NEG_SLOPE * z); p0 = fmaf(lz, at4.w, p0);
        z = a1.x + fmaf(w1, we4.x, xr4.x); lz = fmaxf(z, NEG_SLOPE * z); p1 = fmaf(lz, at4.x, p1);
        z = a1.y + fmaf(w1, we4.y, xr4.y); lz = fmaxf(z, NEG_SLOPE * z); p1 = fmaf(lz, at4.y, p1);
        z = a1.z + fmaf(w1, we4.z, xr4.z); lz = fmaxf(z, NEG_SLOPE * z); p1 = fmaf(lz, at4.z, p1);
        z = a1.w + fmaf(w1, we4.w, xr4.w); lz = fmaxf(z, NEG_SLOPE * z); p1 = fmaf(lz, at4.w, p1);
        p0 += __shfl_xor(p0, 1); p1 += __shfl_xor(p1, 1);
        p0 += __shfl_xor(p0, 2); p1 += __shfl_xor(p1, 2);
        p0 += __shfl_xor(p0, 4); p1 += __shfl_xor(p1, 4);
        if (j + 1 >= dg) p1 = -1e30f;
        float pm = fmaxf(p0, p1);
        if (__any(pm > m + RESCALE_THR)) {
            float nm = fmaxf(m, pm);
            float sc = __expf(m - nm);
            d *= sc;
            acc.x *= sc; acc.y *= sc; acc.z *= sc; acc.w *= sc;
            m = nm;
        }
        float e0 = __expf(p0 - m), e1 = __expf(p1 - m);
        d += e0 + e1;
        acc.x = fmaf(e1, a1.x, fmaf(e0, a0.x, acc.x));
        acc.y = fmaf(e1, a1.y, fmaf(e0, a0.y, acc.y));
        acc.z = fmaf(e1, a1.z, fmaf(e0, a0.z, acc.z));
        acc.w = fmaf(e1, a1.w, fmaf(e0, a0.w, acc.w));
    }
    float inv = 1.f / (d + 1e-16f);
    float4 b4 = ((const float4*)b1)[lane];
    ushort4 o;
    o.x = f2b(fmaxf(fmaf(acc.x, inv, b4.x), 0.f));
    o.y = f2b(fmaxf(fmaf(acc.y, inv, b4.y), 0.f));
    o.z = f2b(fmaxf(fmaf(acc.z, inv, b4.z), 0.f));
    o.w = f2b(fmaxf(fmaf(acc.w, inv, b4.w), 0.f));
    *(ushort4*)(out1 + (size_t)wid * 256 + 4 * lane) = o;
}

// ---- fused layer-2 + pool: 8 threads per node; thread owns 4 of 32 channels ----
// xlr2: [N][64] bf16 (cols 0..31 = xl, 32..63 = xr)
__global__ __launch_bounds__(256) void k_gat2(
    const unsigned short* __restrict__ xlr2,
    const int* __restrict__ start, const int* __restrict__ deg,
    const int2* __restrict__ csr,
    const float* __restrict__ We, const float* __restrict__ att,
    const float* __restrict__ b2, const int* __restrict__ batch,
    float* __restrict__ pool, float* __restrict__ cnt)
{
    int gt = blockIdx.x * blockDim.x + threadIdx.x;
    int i = gt >> 3, g = gt & 7;
    if (i >= N_NODES) return;
    float4 we4 = ((const float4*)We)[g];
    float4 at4 = ((const float4*)att)[g];
    float4 xr4 = u4f(*(const ushort4*)(xlr2 + (size_t)i * 64 + 32 + 4 * g));
    int s0 = start[i], dg = deg[i];
    const int2* ep = csr + s0;
    float m = -1e30f, d = 0.f;
    float4 acc = {0.f, 0.f, 0.f, 0.f};

    int2 ec0 = ep[0];
    int2 ec1 = ep[dg > 1 ? 1 : 0];
    ushort4 ra0 = *(const ushort4*)(xlr2 + ((size_t)ec0.x << 6) + 4 * g);
    ushort4 ra1 = *(const ushort4*)(xlr2 + ((size_t)ec1.x << 6) + 4 * g);

    for (int j = 0; j < dg; j += 2) {
        int2 c0 = ec0, c1 = ec1;
        ushort4 A0 = ra0, A1 = ra1;
        int jn = j + 2;
        if (jn < dg) {
            ec0 = ep[jn];
            ec1 = ep[(jn + 1 < dg) ? jn + 1 : jn];
            ra0 = *(const ushort4*)(xlr2 + ((size_t)ec0.x << 6) + 4 * g);
            ra1 = *(const ushort4*)(xlr2 + ((size_t)ec1.x << 6) + 4 * g);
        }
        float w0 = __int_as_float(c0.y), w1 = __int_as_float(c1.y);
        float4 a0 = u4f(A0), a1 = u4f(A1);
        float p0 = 0.f, p1 = 0.f, z, lz;
        z = a0.x + fmaf(w0, we4.x, xr4.x); lz = fmaxf(z, NEG_SLOPE * z); p0 = fmaf(lz, at4.x, p0);
        z = a0.y + fmaf(w0, we4.y, xr4.y); lz = fmaxf(z, NEG_SLOPE * z); p0 = fmaf(lz, at4.y, p0);
        z = a0.z + fmaf(w0, we4.z, xr4.z); lz = fmaxf(z, NEG_SLOPE * z); p0 = fmaf(lz, at4.z, p0);
        z = a0.w + fmaf(w0, we4.w, xr4.w); lz = fmaxf(z, NEG_SLOPE * z); p0 = fmaf(lz, at4.w, p0);
        z = a1.x + fmaf(w1, we4.x, xr4.x); lz = fmaxf(z, NEG_SLOPE * z); p1 = fmaf(lz, at4.x, p1);
        z = a1.y + fmaf(w1, we4.y, xr4.y); lz = fmaxf(z, NEG_SLOPE * z); p1 = fmaf(lz, at4.y, p1);
        z = a1.z + fmaf(w1, we4.z, xr4.z); lz = fmaxf(z, NEG_SLOPE * z); p1 = fmaf(lz, at4.z, p1);
        z = a1.w + fmaf(w1, we4.w, xr4.w); lz = fmaxf(z, NEG_SLOPE * z); p1 = fmaf(lz, at4.w, p1);
        p0 += __shfl_xor(p0, 1); p1 += __shfl_xor(p1, 1);
        p0 += __shfl_xor(p0, 2); p1 += __shfl_xor(p1, 2);
        p0 += __shfl_xor(p0, 4); p1 += __shfl_xor(p1, 4);
        if (j + 1 >= dg) p1 = -1e30f;
        float pm = fmaxf(p0, p1);
        if (__any(pm > m + RESCALE_THR)) {
            float nm = fmaxf(m, pm);
            float sc = __expf(m - nm);
            d *= sc;
            acc.x *= sc; acc.y *= sc; acc.z *= sc; acc.w *= sc;
            m = nm;
        }
        float e0 = __expf(p0 - m), e1 = __expf(p1 - m);
        d += e0 + e1;
        acc.x = fmaf(e1, a1.x, fmaf(e0, a0.x, acc.x));
        acc.y = fmaf(e1, a1.y, fmaf(e0, a0.y, acc.y));
        acc.z = fmaf(e1, a1.z, fmaf(e0, a0.z, acc.z));
        acc.w = fmaf(e1, a1.w, fmaf(e0, a0.w, acc.w));
    }
    float inv = 1.f / (d + 1e-16f);
    float4 b4 = ((const float4*)b2)[g];
    float vx = fmaxf(fmaf(acc.x, inv, b4.x), 0.f);
    float vy = fmaxf(fmaf(acc.y, inv, b4.y), 0.f);
    float vz = fmaxf(fmaf(acc.z, inv, b4.z), 0.f);
    float vw = fmaxf(fmaf(acc.w, inv, b4.w), 0.f);
    int b = batch[i];
    float* o = pool + (size_t)b * D_H + g * 4;
    atomicAdd(o + 0, vx);
    atomicAdd(o + 1, vy);
    atomicAdd(o + 2, vz);
    atomicAdd(o + 3, vw);
    if (g == 0) atomicAdd(&cnt[b], 1.0f);
}

// ---- mean, sigmoid, final FC ----
__global__ void k_final(const float* __restrict__ pool, const float* __restrict__ cnt,
                        const float* __restrict__ Wfc, const float* __restrict__ bfc,
                        float* __restrict__ out)
{
    int b = blockIdx.x * blockDim.x + threadIdx.x;
    if (b >= N_GRAPHS) return;
    float c = cnt[b]; c = c > 1.f ? c : 1.f;
    float acc = 0.f;
    #pragma unroll
    for (int j = 0; j < D_H; ++j) {
        float f = pool[b * D_H + j] / c;
        f = 1.f / (1.f + __expf(-f));
        acc = fmaf(f, Wfc[j], acc);
    }
    out[b] = acc + bfc[0];
}

extern "C" void kernel_launch(void* const* d_in, const int* in_sizes, int n_in,
                              void* d_out, int out_size, void* d_ws, size_t ws_size,
                              hipStream_t stream)
{
    const float* x    = (const float*)d_in[0];
    const int*   ei   = (const int*)  d_in[1];
    const int*   batch= (const int*)  d_in[2];
    const float* ew   = (const float*)d_in[3];
    const float* Wl1  = (const float*)d_in[4];
    const float* Wr1  = (const float*)d_in[5];
    const float* We1  = (const float*)d_in[6];
    const float* att1 = (const float*)d_in[7];
    const float* b1   = (const float*)d_in[8];
    const float* Wl2  = (const float*)d_in[9];
    const float* Wr2  = (const float*)d_in[10];
    const float* We2  = (const float*)d_in[11];
    const float* att2 = (const float*)d_in[12];
    const float* b2   = (const float*)d_in[13];
    const float* Wfc  = (const float*)d_in[14];
    const float* bfc  = (const float*)d_in[15];
    float* out = (float*)d_out;

    float* ws = (float*)d_ws;
    size_t off = 0;
    auto take = [&](size_t n) -> float* {
        float* p = ws + off;
        off = (off + n + 63) & ~(size_t)63;
        return p;
    };
    // --- zero-initialized region ---
    float* fillsum = take(1);
    int*   deg  = (int*)take(N_NODES);
    int*   cur  = (int*)take(N_NODES);
    float* cnt  = take(N_GRAPHS);
    float* pool = take((size_t)N_GRAPHS * D_H);
    size_t zero_elems = off;
    // --- written-before-read buffers ---
    int*   start = (int*)take(N_NODES);
    int*   bsum  = (int*)take(256);
    int2*  csr   = (int2*)take((size_t)E_TOT * 2);
    unsigned short* xb   = (unsigned short*)take((size_t)N_NODES * D_IN / 2);
    unsigned short* Wt1  = (unsigned short*)take(512 * 128 / 2);
    unsigned short* Wt2  = (unsigned short*)take(64 * 256 / 2);
    unsigned short* xlr1 = (unsigned short*)take((size_t)N_NODES * 512 / 2);
    unsigned short* out1 = (unsigned short*)take((size_t)N_NODES * 256 / 2);
    unsigned short* xlr2 = (unsigned short*)take((size_t)N_NODES * 64 / 2);
    (void)ws_size; (void)in_sizes; (void)n_in; (void)out_size;

    hipMemsetAsync(d_ws, 0, zero_elems * sizeof(float), stream);

    // fill-value sum + degree histogram (fused)
    k_hist_sum<<<(E_TOT + 255) / 256, 256, 0, stream>>>(ei, ew, deg, fillsum);
    k_scan1<<<NSCAN_BLK, 256, 0, stream>>>(deg, start, bsum);
    k_scan2<<<1, 256, 0, stream>>>(bsum, NSCAN_BLK);
    k_scan3<<<NSCAN_BLK, 256, 0, stream>>>(start, bsum);
    k_scatter<<<(E_TOT + 255) / 256, 256, 0, stream>>>(ei, ew, fillsum, start, cur, csr);

    // bf16 prep (fused cast + both weight panels)
    k_prep<<<CAST_BLK + W1_BLK + W2_BLK, 256, 0, stream>>>(
        x, Wl1, Wr1, Wl2, Wr2, xb, Wt1, Wt2);

    // layer-1 projection: xlr1 = xb @ [Wl1|Wr1]  (M=50000, N=512, K=128)
    k_gemm_bf16<128><<<dim3(512 / 64, (N_NODES + 63) / 64), 256, 0, stream>>>(
        xb, Wt1, xlr1, N_NODES, 512);

    // fused layer-1 edge phase
    k_gat1<<<(N_NODES * 64 + 255) / 256, 256, 0, stream>>>(
        xlr1, start, deg, csr, We1, att1, b1, out1);

    // layer-2 projection: xlr2 = out1 @ [Wl2|Wr2]  (M=50000, N=64, K=256)
    k_gemm_bf16<256><<<dim3(64 / 64, (N_NODES + 63) / 64), 256, 0, stream>>>(
        out1, Wt2, xlr2, N_NODES, 64);

    // fused layer-2 edge phase + pooling
    k_gat2<<<((size_t)N_NODES * 8 + 255) / 256, 256, 0, stream>>>(
        xlr2, start, deg, csr, We2, att2, b2, batch, pool, cnt);

    // final FC
    k_final<<<(N_GRAPHS + 255) / 256, 256, 0, stream>>>(pool, cnt, Wfc, bfc, out);
}

// Round 5
// 346.330 us; speedup vs baseline: 1.3623x; 1.3623x over previous
//
#include <hip/hip_runtime.h>
#include <math.h>

#define N_NODES 50000
#define N_EDGES 800000
#define D_IN    128
#define D_H     32
#define N_HEADS 8
#define N_GRAPHS 512
#define E_TOT   (N_EDGES + N_NODES)      // 850000 (with self-loops)
#define HDIM    (N_HEADS * D_H)          // 256
#define NEG_SLOPE 0.2f
#define NSCAN_BLK ((N_NODES + 255) / 256)   // 196
#define RESCALE_THR 8.0f

typedef short bfrag8 __attribute__((ext_vector_type(8)));   // 8 bf16 = 4 VGPRs
typedef float f32x4 __attribute__((ext_vector_type(4)));

// ---- bf16 helpers ----
__device__ __forceinline__ float b2f(unsigned short u) {
    return __uint_as_float(((unsigned)u) << 16);
}
__device__ __forceinline__ unsigned short f2b(float x) {
    unsigned u = __float_as_uint(x);
    unsigned r = u + 0x7FFFu + ((u >> 16) & 1u);   // round-to-nearest-even
    return (unsigned short)(r >> 16);
}
__device__ __forceinline__ float4 u4f(ushort4 u) {
    float4 f;
    f.x = b2f(u.x); f.y = b2f(u.y); f.z = b2f(u.z); f.w = b2f(u.w);
    return f;
}

// ---- sum-reduce edge_weight (fill value = mean); ONE atomic per block ----
__global__ void k_reduce_sum(const float* __restrict__ ew, float* __restrict__ out, int n) {
    int t = blockIdx.x * blockDim.x + threadIdx.x;
    int stride = gridDim.x * blockDim.x;
    float s = 0.f;
    for (int i = t; i < n; i += stride) s += ew[i];
    for (int m = 1; m < 64; m <<= 1) s += __shfl_xor(s, m);
    __shared__ float ls[4];
    int lane = threadIdx.x & 63, wv = threadIdx.x >> 6;
    if (lane == 0) ls[wv] = s;
    __syncthreads();
    if (threadIdx.x == 0) atomicAdd(out, ls[0] + ls[1] + ls[2] + ls[3]);
}

// ---- destination histogram ----
__global__ void k_hist(const int* __restrict__ ei, int* __restrict__ deg) {
    int e = blockIdx.x * blockDim.x + threadIdx.x;
    if (e >= E_TOT) return;
    int dst = (e < N_EDGES) ? ei[N_EDGES + e] : (e - N_EDGES);
    atomicAdd(&deg[dst], 1);
}

// ---- CSR scan (exclusive) ----
__global__ void k_scan1(const int* __restrict__ deg, int* __restrict__ start,
                        int* __restrict__ bsum) {
    __shared__ int sh[256];
    int i = blockIdx.x * 256 + threadIdx.x;
    int v = (i < N_NODES) ? deg[i] : 0;
    sh[threadIdx.x] = v;
    __syncthreads();
    for (int o = 1; o < 256; o <<= 1) {
        int t = (threadIdx.x >= o) ? sh[threadIdx.x - o] : 0;
        __syncthreads();
        sh[threadIdx.x] += t;
        __syncthreads();
    }
    if (i < N_NODES) start[i] = sh[threadIdx.x] - v;
    if (threadIdx.x == 255) bsum[blockIdx.x] = sh[255];
}
__global__ void k_scan2(int* __restrict__ bsum, int nb) {
    __shared__ int sh[256];
    int v = (threadIdx.x < nb) ? bsum[threadIdx.x] : 0;
    sh[threadIdx.x] = v;
    __syncthreads();
    for (int o = 1; o < 256; o <<= 1) {
        int t = (threadIdx.x >= o) ? sh[threadIdx.x - o] : 0;
        __syncthreads();
        sh[threadIdx.x] += t;
        __syncthreads();
    }
    if (threadIdx.x < nb) bsum[threadIdx.x] = sh[threadIdx.x] - v;
}
// also seeds cur[] = start[] so the scatter needs only one atomic per edge
__global__ void k_scan3(int* __restrict__ start, const int* __restrict__ bsum,
                        int* __restrict__ cur) {
    int i = blockIdx.x * 256 + threadIdx.x;
    if (i < N_NODES) {
        int v = start[i] + bsum[blockIdx.x];
        start[i] = v;
        cur[i] = v;
    }
}

// ---- CSR scatter: packed (src, w) int2; position straight from cur ----
__global__ void k_scatter(const int* __restrict__ ei, const float* __restrict__ ew,
                          const float* __restrict__ fillsum,
                          int* __restrict__ cur, int2* __restrict__ csr) {
    int e = blockIdx.x * blockDim.x + threadIdx.x;
    if (e >= E_TOT) return;
    int src, dst; float w;
    if (e < N_EDGES) { src = ei[e]; dst = ei[N_EDGES + e]; w = ew[e]; }
    else { src = dst = e - N_EDGES; w = fillsum[0] * (1.0f / N_EDGES); }
    int pos = atomicAdd(&cur[dst], 1);
    csr[pos] = make_int2(src, __float_as_int(w));
}

// ---- fused prep: cast x to bf16 + build transposed bf16 weight panels ----
#define NC4      (N_NODES * D_IN / 4)        // 1,600,000 ushort4 casts
#define CAST_BLK ((NC4 + 255) / 256)         // 6250
#define W1_BLK   (512 * 128 / 256)           // 256
#define W2_BLK   (64 * 256 / 256)            // 64
__global__ void k_prep(const float* __restrict__ x,
                       const float* __restrict__ Wl1, const float* __restrict__ Wr1,
                       const float* __restrict__ Wl2, const float* __restrict__ Wr2,
                       unsigned short* __restrict__ xb,
                       unsigned short* __restrict__ Wt1,
                       unsigned short* __restrict__ Wt2) {
    int b = blockIdx.x;
    if (b < CAST_BLK) {
        int t = b * 256 + threadIdx.x;
        if (t >= NC4) return;
        float4 v = ((const float4*)x)[t];
        ushort4 o;
        o.x = f2b(v.x); o.y = f2b(v.y); o.z = f2b(v.z); o.w = f2b(v.w);
        ((ushort4*)xb)[t] = o;
    } else if (b < CAST_BLK + W1_BLK) {
        int t = (b - CAST_BLK) * 256 + threadIdx.x;   // t = c*128 + k
        int c = t >> 7, k = t & 127;
        float v = (c < 256) ? Wl1[k * 256 + c] : Wr1[k * 256 + (c - 256)];
        Wt1[t] = f2b(v);
    } else {
        int t = (b - CAST_BLK - W1_BLK) * 256 + threadIdx.x;   // t = c*256 + k
        int c = t >> 8, k = t & 255;
        float v = (c < 32) ? Wl2[k * 32 + c] : Wr2[k * 32 + (c - 32)];
        Wt2[t] = f2b(v);
    }
}

// ---- bf16 MFMA GEMM: C[M,N] = A[M,KC] * Bt[N,KC]^T, all bf16 row-major ----
template <int KC>
__global__ __launch_bounds__(256) void k_gemm_bf16(
    const unsigned short* __restrict__ A, const unsigned short* __restrict__ Bt,
    unsigned short* __restrict__ C, int M, int N)
{
    __shared__ unsigned short A_lds[64][KC + 8];
    __shared__ unsigned short B_lds[64][KC + 8];
    int row0 = blockIdx.y * 64, col0 = blockIdx.x * 64;
    int tid = threadIdx.x;
    const int CPR = KC / 8;
    for (int idx = tid; idx < 64 * CPR; idx += 256) {
        int r = idx / CPR, ch = idx % CPR;
        int gr = row0 + r;
        uint4 v = {0u, 0u, 0u, 0u};
        if (gr < M) v = *(const uint4*)(A + (size_t)gr * KC + ch * 8);
        *(uint4*)&A_lds[r][ch * 8] = v;
    }
    for (int idx = tid; idx < 64 * CPR; idx += 256) {
        int r = idx / CPR, ch = idx % CPR;
        uint4 v = *(const uint4*)(Bt + (size_t)(col0 + r) * KC + ch * 8);
        *(uint4*)&B_lds[r][ch * 8] = v;
    }
    __syncthreads();

    int wid = tid >> 6, lane = tid & 63;
    int wy = wid >> 1, wx = wid & 1;
    int lr = lane & 15, lh = lane >> 4;
    f32x4 acc[2][2] = {};
    #pragma unroll
    for (int k0 = 0; k0 < KC; k0 += 32) {
        bfrag8 a0 = *(const bfrag8*)&A_lds[32 * wy + lr][k0 + lh * 8];
        bfrag8 a1 = *(const bfrag8*)&A_lds[32 * wy + 16 + lr][k0 + lh * 8];
        bfrag8 b0 = *(const bfrag8*)&B_lds[32 * wx + lr][k0 + lh * 8];
        bfrag8 b1 = *(const bfrag8*)&B_lds[32 * wx + 16 + lr][k0 + lh * 8];
        acc[0][0] = __builtin_amdgcn_mfma_f32_16x16x32_bf16(a0, b0, acc[0][0], 0, 0, 0);
        acc[0][1] = __builtin_amdgcn_mfma_f32_16x16x32_bf16(a0, b1, acc[0][1], 0, 0, 0);
        acc[1][0] = __builtin_amdgcn_mfma_f32_16x16x32_bf16(a1, b0, acc[1][0], 0, 0, 0);
        acc[1][1] = __builtin_amdgcn_mfma_f32_16x16x32_bf16(a1, b1, acc[1][1], 0, 0, 0);
    }
    #pragma unroll
    for (int mt = 0; mt < 2; ++mt) {
        #pragma unroll
        for (int nt = 0; nt < 2; ++nt) {
            #pragma unroll
            for (int r = 0; r < 4; ++r) {
                int row = row0 + 32 * wy + 16 * mt + lh * 4 + r;
                if (row < M)
                    C[(size_t)row * N + col0 + 32 * wx + 16 * nt + lr] = f2b(acc[mt][nt][r]);
            }
        }
    }
}

// ---- fused layer-1: one wave per node; lane owns 4 of 256 channels ----
// xlr: [N][512] bf16 (cols 0..255 = xl, 256..511 = xr). 2-edge unroll +
// deferred-rescale online softmax. out1: [N][256] bf16.
__global__ __launch_bounds__(256) void k_gat1(
    const unsigned short* __restrict__ xlr,
    const int* __restrict__ start, const int* __restrict__ deg,
    const int2* __restrict__ csr,
    const float* __restrict__ We, const float* __restrict__ att,
    const float* __restrict__ b1, unsigned short* __restrict__ out1)
{
    int wid = (blockIdx.x * blockDim.x + threadIdx.x) >> 6;
    int lane = threadIdx.x & 63;
    if (wid >= N_NODES) return;
    float4 we4 = ((const float4*)We)[lane];
    float4 at4 = ((const float4*)att)[lane];
    float4 xr4 = u4f(*(const ushort4*)(xlr + (size_t)wid * 512 + 256 + 4 * lane));
    int s0 = start[wid], dg = deg[wid];
    const int2* ep = csr + s0;
    float m = -1e30f, d = 0.f;
    float4 acc = {0.f, 0.f, 0.f, 0.f};

    int2 ec0 = ep[0];
    int2 ec1 = ep[dg > 1 ? 1 : 0];
    ushort4 ra0 = *(const ushort4*)(xlr + ((size_t)ec0.x << 9) + 4 * lane);
    ushort4 ra1 = *(const ushort4*)(xlr + ((size_t)ec1.x << 9) + 4 * lane);

    for (int j = 0; j < dg; j += 2) {
        int2 c0 = ec0, c1 = ec1;
        ushort4 A0 = ra0, A1 = ra1;
        int jn = j + 2;
        if (jn < dg) {
            ec0 = ep[jn];
            ec1 = ep[(jn + 1 < dg) ? jn + 1 : jn];
            ra0 = *(const ushort4*)(xlr + ((size_t)ec0.x << 9) + 4 * lane);
            ra1 = *(const ushort4*)(xlr + ((size_t)ec1.x << 9) + 4 * lane);
        }
        float w0 = __int_as_float(c0.y), w1 = __int_as_float(c1.y);
        float4 a0 = u4f(A0), a1 = u4f(A1);
        float p0 = 0.f, p1 = 0.f, z, lz;
        z = a0.x + fmaf(w0, we4.x, xr4.x); lz = fmaxf(z, NEG_SLOPE * z); p0 = fmaf(lz, at4.x, p0);
        z = a0.y + fmaf(w0, we4.y, xr4.y); lz = fmaxf(z, NEG_SLOPE * z); p0 = fmaf(lz, at4.y, p0);
        z = a0.z + fmaf(w0, we4.z, xr4.z); lz = fmaxf(z, NEG_SLOPE * z); p0 = fmaf(lz, at4.z, p0);
        z = a0.w + fmaf(w0, we4.w, xr4.w); lz = fmaxf(z, NEG_SLOPE * z); p0 = fmaf(lz, at4.w, p0);
        z = a1.x + fmaf(w1, we4.x, xr4.x); lz = fmaxf(z, NEG_SLOPE * z); p1 = fmaf(lz, at4.x, p1);
        z = a1.y + fmaf(w1, we4.y, xr4.y); lz = fmaxf(z, NEG_SLOPE * z); p1 = fmaf(lz, at4.y, p1);
        z = a1.z + fmaf(w1, we4.z, xr4.z); lz = fmaxf(z, NEG_SLOPE * z); p1 = fmaf(lz, at4.z, p1);
        z = a1.w + fmaf(w1, we4.w, xr4.w); lz = fmaxf(z, NEG_SLOPE * z); p1 = fmaf(lz, at4.w, p1);
        p0 += __shfl_xor(p0, 1); p1 += __shfl_xor(p1, 1);
        p0 += __shfl_xor(p0, 2); p1 += __shfl_xor(p1, 2);
        p0 += __shfl_xor(p0, 4); p1 += __shfl_xor(p1, 4);
        if (j + 1 >= dg) p1 = -1e30f;
        float pm = fmaxf(p0, p1);
        if (__any(pm > m + RESCALE_THR)) {
            float nm = fmaxf(m, pm);
            float sc = __expf(m - nm);
            d *= sc;
            acc.x *= sc; acc.y *= sc; acc.z *= sc; acc.w *= sc;
            m = nm;
        }
        float e0 = __expf(p0 - m), e1 = __expf(p1 - m);
        d += e0 + e1;
        acc.x = fmaf(e1, a1.x, fmaf(e0, a0.x, acc.x));
        acc.y = fmaf(e1, a1.y, fmaf(e0, a0.y, acc.y));
        acc.z = fmaf(e1, a1.z, fmaf(e0, a0.z, acc.z));
        acc.w = fmaf(e1, a1.w, fmaf(e0, a0.w, acc.w));
    }
    float inv = 1.f / (d + 1e-16f);
    float4 b4 = ((const float4*)b1)[lane];
    ushort4 o;
    o.x = f2b(fmaxf(fmaf(acc.x, inv, b4.x), 0.f));
    o.y = f2b(fmaxf(fmaf(acc.y, inv, b4.y), 0.f));
    o.z = f2b(fmaxf(fmaf(acc.z, inv, b4.z), 0.f));
    o.w = f2b(fmaxf(fmaf(acc.w, inv, b4.w), 0.f));
    *(ushort4*)(out1 + (size_t)wid * 256 + 4 * lane) = o;
}

// ---- fused layer-2 + pool: 8 threads per node; thread owns 4 of 32 channels ----
// xlr2: [N][64] bf16 (cols 0..31 = xl, 32..63 = xr)
__global__ __launch_bounds__(256) void k_gat2(
    const unsigned short* __restrict__ xlr2,
    const int* __restrict__ start, const int* __restrict__ deg,
    const int2* __restrict__ csr,
    const float* __restrict__ We, const float* __restrict__ att,
    const float* __restrict__ b2, const int* __restrict__ batch,
    float* __restrict__ pool, float* __restrict__ cnt)
{
    int gt = blockIdx.x * blockDim.x + threadIdx.x;
    int i = gt >> 3, g = gt & 7;
    if (i >= N_NODES) return;
    float4 we4 = ((const float4*)We)[g];
    float4 at4 = ((const float4*)att)[g];
    float4 xr4 = u4f(*(const ushort4*)(xlr2 + (size_t)i * 64 + 32 + 4 * g));
    int s0 = start[i], dg = deg[i];
    const int2* ep = csr + s0;
    float m = -1e30f, d = 0.f;
    float4 acc = {0.f, 0.f, 0.f, 0.f};

    int2 ec0 = ep[0];
    int2 ec1 = ep[dg > 1 ? 1 : 0];
    ushort4 ra0 = *(const ushort4*)(xlr2 + ((size_t)ec0.x << 6) + 4 * g);
    ushort4 ra1 = *(const ushort4*)(xlr2 + ((size_t)ec1.x << 6) + 4 * g);

    for (int j = 0; j < dg; j += 2) {
        int2 c0 = ec0, c1 = ec1;
        ushort4 A0 = ra0, A1 = ra1;
        int jn = j + 2;
        if (jn < dg) {
            ec0 = ep[jn];
            ec1 = ep[(jn + 1 < dg) ? jn + 1 : jn];
            ra0 = *(const ushort4*)(xlr2 + ((size_t)ec0.x << 6) + 4 * g);
            ra1 = *(const ushort4*)(xlr2 + ((size_t)ec1.x << 6) + 4 * g);
        }
        float w0 = __int_as_float(c0.y), w1 = __int_as_float(c1.y);
        float4 a0 = u4f(A0), a1 = u4f(A1);
        float p0 = 0.f, p1 = 0.f, z, lz;
        z = a0.x + fmaf(w0, we4.x, xr4.x); lz = fmaxf(z, NEG_SLOPE * z); p0 = fmaf(lz, at4.x, p0);
        z = a0.y + fmaf(w0, we4.y, xr4.y); lz = fmaxf(z, NEG_SLOPE * z); p0 = fmaf(lz, at4.y, p0);
        z = a0.z + fmaf(w0, we4.z, xr4.z); lz = fmaxf(z, NEG_SLOPE * z); p0 = fmaf(lz, at4.z, p0);
        z = a0.w + fmaf(w0, we4.w, xr4.w); lz = fmaxf(z, NEG_SLOPE * z); p0 = fmaf(lz, at4.w, p0);
        z = a1.x + fmaf(w1, we4.x, xr4.x); lz = fmaxf(z, NEG_SLOPE * z); p1 = fmaf(lz, at4.x, p1);
        z = a1.y + fmaf(w1, we4.y, xr4.y); lz = fmaxf(z, NEG_SLOPE * z); p1 = fmaf(lz, at4.y, p1);
        z = a1.z + fmaf(w1, we4.z, xr4.z); lz = fmaxf(z, NEG_SLOPE * z); p1 = fmaf(lz, at4.z, p1);
        z = a1.w + fmaf(w1, we4.w, xr4.w); lz = fmaxf(z, NEG_SLOPE * z); p1 = fmaf(lz, at4.w, p1);
        p0 += __shfl_xor(p0, 1); p1 += __shfl_xor(p1, 1);
        p0 += __shfl_xor(p0, 2); p1 += __shfl_xor(p1, 2);
        p0 += __shfl_xor(p0, 4); p1 += __shfl_xor(p1, 4);
        if (j + 1 >= dg) p1 = -1e30f;
        float pm = fmaxf(p0, p1);
        if (__any(pm > m + RESCALE_THR)) {
            float nm = fmaxf(m, pm);
            float sc = __expf(m - nm);
            d *= sc;
            acc.x *= sc; acc.y *= sc; acc.z *= sc; acc.w *= sc;
            m = nm;
        }
        float e0 = __expf(p0 - m), e1 = __expf(p1 - m);
        d += e0 + e1;
        acc.x = fmaf(e1, a1.x, fmaf(e0, a0.x, acc.x));
        acc.y = fmaf(e1, a1.y, fmaf(e0, a0.y, acc.y));
        acc.z = fmaf(e1, a1.z, fmaf(e0, a0.z, acc.z));
        acc.w = fmaf(e1, a1.w, fmaf(e0, a0.w, acc.w));
    }
    float inv = 1.f / (d + 1e-16f);
    float4 b4 = ((const float4*)b2)[g];
    float vx = fmaxf(fmaf(acc.x, inv, b4.x), 0.f);
    float vy = fmaxf(fmaf(acc.y, inv, b4.y), 0.f);
    float vz = fmaxf(fmaf(acc.z, inv, b4.z), 0.f);
    float vw = fmaxf(fmaf(acc.w, inv, b4.w), 0.f);
    int b = batch[i];
    float* o = pool + (size_t)b * D_H + g * 4;
    atomicAdd(o + 0, vx);
    atomicAdd(o + 1, vy);
    atomicAdd(o + 2, vz);
    atomicAdd(o + 3, vw);
    if (g == 0) atomicAdd(&cnt[b], 1.0f);
}

// ---- mean, sigmoid, final FC ----
__global__ void k_final(const float* __restrict__ pool, const float* __restrict__ cnt,
                        const float* __restrict__ Wfc, const float* __restrict__ bfc,
                        float* __restrict__ out)
{
    int b = blockIdx.x * blockDim.x + threadIdx.x;
    if (b >= N_GRAPHS) return;
    float c = cnt[b]; c = c > 1.f ? c : 1.f;
    float acc = 0.f;
    #pragma unroll
    for (int j = 0; j < D_H; ++j) {
        float f = pool[b * D_H + j] / c;
        f = 1.f / (1.f + __expf(-f));
        acc = fmaf(f, Wfc[j], acc);
    }
    out[b] = acc + bfc[0];
}

extern "C" void kernel_launch(void* const* d_in, const int* in_sizes, int n_in,
                              void* d_out, int out_size, void* d_ws, size_t ws_size,
                              hipStream_t stream)
{
    const float* x    = (const float*)d_in[0];
    const int*   ei   = (const int*)  d_in[1];
    const int*   batch= (const int*)  d_in[2];
    const float* ew   = (const float*)d_in[3];
    const float* Wl1  = (const float*)d_in[4];
    const float* Wr1  = (const float*)d_in[5];
    const float* We1  = (const float*)d_in[6];
    const float* att1 = (const float*)d_in[7];
    const float* b1   = (const float*)d_in[8];
    const float* Wl2  = (const float*)d_in[9];
    const float* Wr2  = (const float*)d_in[10];
    const float* We2  = (const float*)d_in[11];
    const float* att2 = (const float*)d_in[12];
    const float* b2   = (const float*)d_in[13];
    const float* Wfc  = (const float*)d_in[14];
    const float* bfc  = (const float*)d_in[15];
    float* out = (float*)d_out;

    float* ws = (float*)d_ws;
    size_t off = 0;
    auto take = [&](size_t n) -> float* {
        float* p = ws + off;
        off = (off + n + 63) & ~(size_t)63;
        return p;
    };
    // --- zero-initialized region ---
    float* fillsum = take(1);
    int*   deg  = (int*)take(N_NODES);
    float* cnt  = take(N_GRAPHS);
    float* pool = take((size_t)N_GRAPHS * D_H);
    size_t zero_elems = off;
    // --- written-before-read buffers ---
    int*   start = (int*)take(N_NODES);
    int*   cur   = (int*)take(N_NODES);
    int*   bsum  = (int*)take(256);
    int2*  csr   = (int2*)take((size_t)E_TOT * 2);
    unsigned short* xb   = (unsigned short*)take((size_t)N_NODES * D_IN / 2);
    unsigned short* Wt1  = (unsigned short*)take(512 * 128 / 2);
    unsigned short* Wt2  = (unsigned short*)take(64 * 256 / 2);
    unsigned short* xlr1 = (unsigned short*)take((size_t)N_NODES * 512 / 2);
    unsigned short* out1 = (unsigned short*)take((size_t)N_NODES * 256 / 2);
    unsigned short* xlr2 = (unsigned short*)take((size_t)N_NODES * 64 / 2);
    (void)ws_size; (void)in_sizes; (void)n_in; (void)out_size;

    hipMemsetAsync(d_ws, 0, zero_elems * sizeof(float), stream);

    // fill value = mean(edge_weight): 512 blocks, one atomic per block
    k_reduce_sum<<<512, 256, 0, stream>>>(ew, fillsum, N_EDGES);
    // degree histogram (scattered atomics, L2-resident)
    k_hist<<<(E_TOT + 255) / 256, 256, 0, stream>>>(ei, deg);
    k_scan1<<<NSCAN_BLK, 256, 0, stream>>>(deg, start, bsum);
    k_scan2<<<1, 256, 0, stream>>>(bsum, NSCAN_BLK);
    k_scan3<<<NSCAN_BLK, 256, 0, stream>>>(start, bsum, cur);
    k_scatter<<<(E_TOT + 255) / 256, 256, 0, stream>>>(ei, ew, fillsum, cur, csr);

    // bf16 prep (fused cast + both weight panels)
    k_prep<<<CAST_BLK + W1_BLK + W2_BLK, 256, 0, stream>>>(
        x, Wl1, Wr1, Wl2, Wr2, xb, Wt1, Wt2);

    // layer-1 projection: xlr1 = xb @ [Wl1|Wr1]  (M=50000, N=512, K=128)
    k_gemm_bf16<128><<<dim3(512 / 64, (N_NODES + 63) / 64), 256, 0, stream>>>(
        xb, Wt1, xlr1, N_NODES, 512);

    // fused layer-1 edge phase
    k_gat1<<<(N_NODES * 64 + 255) / 256, 256, 0, stream>>>(
        xlr1, start, deg, csr, We1, att1, b1, out1);

    // layer-2 projection: xlr2 = out1 @ [Wl2|Wr2]  (M=50000, N=64, K=256)
    k_gemm_bf16<256><<<dim3(64 / 64, (N_NODES + 63) / 64), 256, 0, stream>>>(
        out1, Wt2, xlr2, N_NODES, 64);

    // fused layer-2 edge phase + pooling
    k_gat2<<<((size_t)N_NODES * 8 + 255) / 256, 256, 0, stream>>>(
        xlr2, start, deg, csr, We2, att2, b2, batch, pool, cnt);

    // final FC
    k_final<<<(N_GRAPHS + 255) / 256, 256, 0, stream>>>(pool, cnt, Wfc, bfc, out);
}

// Round 6
// 332.835 us; speedup vs baseline: 1.4176x; 1.0405x over previous
//
#include <hip/hip_runtime.h>
#include <math.h>

#define N_NODES 50000
#define N_EDGES 800000
#define D_IN    128
#define D_H     32
#define N_HEADS 8
#define N_GRAPHS 512
#define E_TOT   (N_EDGES + N_NODES)      // 850000 (with self-loops)
#define HDIM    (N_HEADS * D_H)          // 256
#define NEG_SLOPE 0.2f
#define NSCAN_BLK ((N_NODES + 255) / 256)   // 196
#define LOG2E 1.4426950408889634f
#define RESCALE_THR2 11.0f               // ~8 nats in log2 units

typedef short bfrag8 __attribute__((ext_vector_type(8)));   // 8 bf16 = 4 VGPRs
typedef float f32x4 __attribute__((ext_vector_type(4)));
typedef float f32x2 __attribute__((ext_vector_type(2)));

#if __has_builtin(__builtin_amdgcn_exp2f)
#define EXP2(x) __builtin_amdgcn_exp2f(x)
#else
#define EXP2(x) exp2f(x)
#endif

// ---- bf16 helpers ----
__device__ __forceinline__ unsigned short f2b(float x) {
    unsigned u = __float_as_uint(x);
    unsigned r = u + 0x7FFFu + ((u >> 16) & 1u);   // round-to-nearest-even
    return (unsigned short)(r >> 16);
}
// u32 holding two bf16 (lo=ch0, hi=ch1) -> f32x2 {ch0, ch1}
__device__ __forceinline__ f32x2 b2x2(unsigned u) {
    f32x2 v;
    v.x = __uint_as_float(u << 16);
    v.y = __uint_as_float(u & 0xFFFF0000u);
    return v;
}

// ==== fused front kernel: reduce_sum | hist | cast x | weight panels ====
#define RS_BLK   512
#define HIST_BLK ((E_TOT + 255) / 256)       // 3321
#define NC4      (N_NODES * D_IN / 4)        // 1,600,000 ushort4 casts
#define CAST_BLK ((NC4 + 255) / 256)         // 6250
#define W1_BLK   (512 * 128 / 256)           // 256
#define W2_BLK   (64 * 256 / 256)            // 64
__global__ void k_front(const float* __restrict__ ew, const int* __restrict__ ei,
                        const float* __restrict__ x,
                        const float* __restrict__ Wl1, const float* __restrict__ Wr1,
                        const float* __restrict__ Wl2, const float* __restrict__ Wr2,
                        float* __restrict__ fillsum, int* __restrict__ deg,
                        unsigned short* __restrict__ xb,
                        unsigned short* __restrict__ Wt1,
                        unsigned short* __restrict__ Wt2) {
    __shared__ float ls[4];
    int b = blockIdx.x;
    if (b < RS_BLK) {
        // edge-weight sum, ONE atomic per block
        int t = b * 256 + threadIdx.x;
        float s = 0.f;
        for (int i = t; i < N_EDGES; i += RS_BLK * 256) s += ew[i];
        for (int m = 1; m < 64; m <<= 1) s += __shfl_xor(s, m);
        int lane = threadIdx.x & 63, wv = threadIdx.x >> 6;
        if (lane == 0) ls[wv] = s;
        __syncthreads();
        if (threadIdx.x == 0) atomicAdd(fillsum, ls[0] + ls[1] + ls[2] + ls[3]);
    } else if (b < RS_BLK + HIST_BLK) {
        int e = (b - RS_BLK) * 256 + threadIdx.x;
        if (e >= E_TOT) return;
        int dst = (e < N_EDGES) ? ei[N_EDGES + e] : (e - N_EDGES);
        atomicAdd(&deg[dst], 1);
    } else if (b < RS_BLK + HIST_BLK + CAST_BLK) {
        int t = (b - RS_BLK - HIST_BLK) * 256 + threadIdx.x;
        if (t >= NC4) return;
        float4 v = ((const float4*)x)[t];
        ushort4 o;
        o.x = f2b(v.x); o.y = f2b(v.y); o.z = f2b(v.z); o.w = f2b(v.w);
        ((ushort4*)xb)[t] = o;
    } else if (b < RS_BLK + HIST_BLK + CAST_BLK + W1_BLK) {
        int t = (b - RS_BLK - HIST_BLK - CAST_BLK) * 256 + threadIdx.x;  // c*128+k
        int c = t >> 7, k = t & 127;
        float v = (c < 256) ? Wl1[k * 256 + c] : Wr1[k * 256 + (c - 256)];
        Wt1[t] = f2b(v);
    } else {
        int t = (b - RS_BLK - HIST_BLK - CAST_BLK - W1_BLK) * 256 + threadIdx.x; // c*256+k
        int c = t >> 8, k = t & 255;
        float v = (c < 32) ? Wl2[k * 32 + c] : Wr2[k * 32 + (c - 32)];
        Wt2[t] = f2b(v);
    }
}

// ---- CSR scan (exclusive) ----
__global__ void k_scan1(const int* __restrict__ deg, int* __restrict__ start,
                        int* __restrict__ bsum) {
    __shared__ int sh[256];
    int i = blockIdx.x * 256 + threadIdx.x;
    int v = (i < N_NODES) ? deg[i] : 0;
    sh[threadIdx.x] = v;
    __syncthreads();
    for (int o = 1; o < 256; o <<= 1) {
        int t = (threadIdx.x >= o) ? sh[threadIdx.x - o] : 0;
        __syncthreads();
        sh[threadIdx.x] += t;
        __syncthreads();
    }
    if (i < N_NODES) start[i] = sh[threadIdx.x] - v;
    if (threadIdx.x == 255) bsum[blockIdx.x] = sh[255];
}
__global__ void k_scan2(int* __restrict__ bsum, int nb) {
    __shared__ int sh[256];
    int v = (threadIdx.x < nb) ? bsum[threadIdx.x] : 0;
    sh[threadIdx.x] = v;
    __syncthreads();
    for (int o = 1; o < 256; o <<= 1) {
        int t = (threadIdx.x >= o) ? sh[threadIdx.x - o] : 0;
        __syncthreads();
        sh[threadIdx.x] += t;
        __syncthreads();
    }
    if (threadIdx.x < nb) bsum[threadIdx.x] = sh[threadIdx.x] - v;
}
// also seeds cur[] = start[] so the scatter needs only one atomic per edge
__global__ void k_scan3(int* __restrict__ start, const int* __restrict__ bsum,
                        int* __restrict__ cur) {
    int i = blockIdx.x * 256 + threadIdx.x;
    if (i < N_NODES) {
        int v = start[i] + bsum[blockIdx.x];
        start[i] = v;
        cur[i] = v;
    }
}

// ---- CSR scatter: packed (src, w) int2 ----
__global__ void k_scatter(const int* __restrict__ ei, const float* __restrict__ ew,
                          const float* __restrict__ fillsum,
                          int* __restrict__ cur, int2* __restrict__ csr) {
    int e = blockIdx.x * blockDim.x + threadIdx.x;
    if (e >= E_TOT) return;
    int src, dst; float w;
    if (e < N_EDGES) { src = ei[e]; dst = ei[N_EDGES + e]; w = ew[e]; }
    else { src = dst = e - N_EDGES; w = fillsum[0] * (1.0f / N_EDGES); }
    int pos = atomicAdd(&cur[dst], 1);
    csr[pos] = make_int2(src, __float_as_int(w));
}

// ---- bf16 MFMA GEMM: C[M,N] = A[M,KC] * Bt[N,KC]^T, all bf16 row-major ----
template <int KC>
__global__ __launch_bounds__(256) void k_gemm_bf16(
    const unsigned short* __restrict__ A, const unsigned short* __restrict__ Bt,
    unsigned short* __restrict__ C, int M, int N)
{
    __shared__ unsigned short A_lds[64][KC + 8];
    __shared__ unsigned short B_lds[64][KC + 8];
    int row0 = blockIdx.y * 64, col0 = blockIdx.x * 64;
    int tid = threadIdx.x;
    const int CPR = KC / 8;
    for (int idx = tid; idx < 64 * CPR; idx += 256) {
        int r = idx / CPR, ch = idx % CPR;
        int gr = row0 + r;
        uint4 v = {0u, 0u, 0u, 0u};
        if (gr < M) v = *(const uint4*)(A + (size_t)gr * KC + ch * 8);
        *(uint4*)&A_lds[r][ch * 8] = v;
    }
    for (int idx = tid; idx < 64 * CPR; idx += 256) {
        int r = idx / CPR, ch = idx % CPR;
        uint4 v = *(const uint4*)(Bt + (size_t)(col0 + r) * KC + ch * 8);
        *(uint4*)&B_lds[r][ch * 8] = v;
    }
    __syncthreads();

    int wid = tid >> 6, lane = tid & 63;
    int wy = wid >> 1, wx = wid & 1;
    int lr = lane & 15, lh = lane >> 4;
    f32x4 acc[2][2] = {};
    #pragma unroll
    for (int k0 = 0; k0 < KC; k0 += 32) {
        bfrag8 a0 = *(const bfrag8*)&A_lds[32 * wy + lr][k0 + lh * 8];
        bfrag8 a1 = *(const bfrag8*)&A_lds[32 * wy + 16 + lr][k0 + lh * 8];
        bfrag8 b0 = *(const bfrag8*)&B_lds[32 * wx + lr][k0 + lh * 8];
        bfrag8 b1 = *(const bfrag8*)&B_lds[32 * wx + 16 + lr][k0 + lh * 8];
        acc[0][0] = __builtin_amdgcn_mfma_f32_16x16x32_bf16(a0, b0, acc[0][0], 0, 0, 0);
        acc[0][1] = __builtin_amdgcn_mfma_f32_16x16x32_bf16(a0, b1, acc[0][1], 0, 0, 0);
        acc[1][0] = __builtin_amdgcn_mfma_f32_16x16x32_bf16(a1, b0, acc[1][0], 0, 0, 0);
        acc[1][1] = __builtin_amdgcn_mfma_f32_16x16x32_bf16(a1, b1, acc[1][1], 0, 0, 0);
    }
    #pragma unroll
    for (int mt = 0; mt < 2; ++mt) {
        #pragma unroll
        for (int nt = 0; nt < 2; ++nt) {
            #pragma unroll
            for (int r = 0; r < 4; ++r) {
                int row = row0 + 32 * wy + 16 * mt + lh * 4 + r;
                if (row < M)
                    C[(size_t)row * N + col0 + 32 * wx + 16 * nt + lr] = f2b(acc[mt][nt][r]);
            }
        }
    }
}

// ---- fused layer-1: one wave per node; lane owns 4 of 256 channels ----
// Packed f32x2 math; scores in log2 space (att pre-scaled by log2e).
__global__ __launch_bounds__(256) void k_gat1(
    const unsigned short* __restrict__ xlr,
    const int* __restrict__ start, const int* __restrict__ deg,
    const int2* __restrict__ csr,
    const float* __restrict__ We, const float* __restrict__ att,
    const float* __restrict__ b1, unsigned short* __restrict__ out1)
{
    int wid = (blockIdx.x * blockDim.x + threadIdx.x) >> 6;
    int lane = threadIdx.x & 63;
    if (wid >= N_NODES) return;
    f32x2 we01 = ((const f32x2*)We)[2 * lane],  we23 = ((const f32x2*)We)[2 * lane + 1];
    f32x2 at01 = ((const f32x2*)att)[2 * lane], at23 = ((const f32x2*)att)[2 * lane + 1];
    at01 *= LOG2E; at23 *= LOG2E;               // fold ln->log2 into the dot
    uint2 xru = *(const uint2*)(xlr + (size_t)wid * 512 + 256 + 4 * lane);
    f32x2 xr01 = b2x2(xru.x), xr23 = b2x2(xru.y);
    int s0 = start[wid], dg = deg[wid];
    const int2* ep = csr + s0;
    float m = -1e30f, d = 0.f;
    f32x2 acc01 = {0.f, 0.f}, acc23 = {0.f, 0.f};

    int2 ec0 = ep[0];
    int2 ec1 = ep[dg > 1 ? 1 : 0];
    uint2 ra0 = *(const uint2*)(xlr + ((size_t)ec0.x << 9) + 4 * lane);
    uint2 ra1 = *(const uint2*)(xlr + ((size_t)ec1.x << 9) + 4 * lane);

    for (int j = 0; j < dg; j += 2) {
        int2 c0 = ec0, c1 = ec1;
        uint2 A0 = ra0, A1 = ra1;
        int jn = j + 2;
        if (jn < dg) {
            ec0 = ep[jn];
            ec1 = ep[(jn + 1 < dg) ? jn + 1 : jn];
            ra0 = *(const uint2*)(xlr + ((size_t)ec0.x << 9) + 4 * lane);
            ra1 = *(const uint2*)(xlr + ((size_t)ec1.x << 9) + 4 * lane);
        }
        float w0 = __int_as_float(c0.y), w1 = __int_as_float(c1.y);
        f32x2 ww0 = {w0, w0}, ww1 = {w1, w1};
        f32x2 a001 = b2x2(A0.x), a023 = b2x2(A0.y);
        f32x2 a101 = b2x2(A1.x), a123 = b2x2(A1.y);
        // scores (packed): z = a + (w*we + xr); lz = max(z, 0.2z); p += lz*at
        f32x2 p0v = {0.f, 0.f}, p1v = {0.f, 0.f}, z, lz;
        z = a001 + __builtin_elementwise_fma(ww0, we01, xr01);
        lz = __builtin_elementwise_max(z, z * NEG_SLOPE);
        p0v = __builtin_elementwise_fma(lz, at01, p0v);
        z = a023 + __builtin_elementwise_fma(ww0, we23, xr23);
        lz = __builtin_elementwise_max(z, z * NEG_SLOPE);
        p0v = __builtin_elementwise_fma(lz, at23, p0v);
        z = a101 + __builtin_elementwise_fma(ww1, we01, xr01);
        lz = __builtin_elementwise_max(z, z * NEG_SLOPE);
        p1v = __builtin_elementwise_fma(lz, at01, p1v);
        z = a123 + __builtin_elementwise_fma(ww1, we23, xr23);
        lz = __builtin_elementwise_max(z, z * NEG_SLOPE);
        p1v = __builtin_elementwise_fma(lz, at23, p1v);
        float p0 = p0v.x + p0v.y, p1 = p1v.x + p1v.y;
        p0 += __shfl_xor(p0, 1); p1 += __shfl_xor(p1, 1);
        p0 += __shfl_xor(p0, 2); p1 += __shfl_xor(p1, 2);
        p0 += __shfl_xor(p0, 4); p1 += __shfl_xor(p1, 4);
        if (j + 1 >= dg) p1 = -1e30f;
        float pm = fmaxf(p0, p1);
        if (__any(pm > m + RESCALE_THR2)) {
            float nm = fmaxf(m, pm);
            float sc = EXP2(m - nm);
            d *= sc;
            acc01 *= sc; acc23 *= sc;
            m = nm;
        }
        float e0 = EXP2(p0 - m), e1 = EXP2(p1 - m);
        d += e0 + e1;
        f32x2 ee0 = {e0, e0}, ee1 = {e1, e1};
        acc01 = __builtin_elementwise_fma(ee0, a001, acc01);
        acc23 = __builtin_elementwise_fma(ee0, a023, acc23);
        acc01 = __builtin_elementwise_fma(ee1, a101, acc01);
        acc23 = __builtin_elementwise_fma(ee1, a123, acc23);
    }
    float inv = 1.f / (d + 1e-16f);
    f32x2 b01 = ((const f32x2*)b1)[2 * lane], b23 = ((const f32x2*)b1)[2 * lane + 1];
    ushort4 o;
    o.x = f2b(fmaxf(fmaf(acc01.x, inv, b01.x), 0.f));
    o.y = f2b(fmaxf(fmaf(acc01.y, inv, b01.y), 0.f));
    o.z = f2b(fmaxf(fmaf(acc23.x, inv, b23.x), 0.f));
    o.w = f2b(fmaxf(fmaf(acc23.y, inv, b23.y), 0.f));
    *(ushort4*)(out1 + (size_t)wid * 256 + 4 * lane) = o;
}

// ---- fused layer-2 + pool: 8 threads per node; thread owns 4 of 32 channels ----
__global__ __launch_bounds__(256) void k_gat2(
    const unsigned short* __restrict__ xlr2,
    const int* __restrict__ start, const int* __restrict__ deg,
    const int2* __restrict__ csr,
    const float* __restrict__ We, const float* __restrict__ att,
    const float* __restrict__ b2, const int* __restrict__ batch,
    float* __restrict__ pool, float* __restrict__ cnt)
{
    int gt = blockIdx.x * blockDim.x + threadIdx.x;
    int i = gt >> 3, g = gt & 7;
    if (i >= N_NODES) return;
    f32x2 we01 = ((const f32x2*)We)[2 * g],  we23 = ((const f32x2*)We)[2 * g + 1];
    f32x2 at01 = ((const f32x2*)att)[2 * g], at23 = ((const f32x2*)att)[2 * g + 1];
    at01 *= LOG2E; at23 *= LOG2E;
    uint2 xru = *(const uint2*)(xlr2 + (size_t)i * 64 + 32 + 4 * g);
    f32x2 xr01 = b2x2(xru.x), xr23 = b2x2(xru.y);
    int s0 = start[i], dg = deg[i];
    const int2* ep = csr + s0;
    float m = -1e30f, d = 0.f;
    f32x2 acc01 = {0.f, 0.f}, acc23 = {0.f, 0.f};

    int2 ec0 = ep[0];
    int2 ec1 = ep[dg > 1 ? 1 : 0];
    uint2 ra0 = *(const uint2*)(xlr2 + ((size_t)ec0.x << 6) + 4 * g);
    uint2 ra1 = *(const uint2*)(xlr2 + ((size_t)ec1.x << 6) + 4 * g);

    for (int j = 0; j < dg; j += 2) {
        int2 c0 = ec0, c1 = ec1;
        uint2 A0 = ra0, A1 = ra1;
        int jn = j + 2;
        if (jn < dg) {
            ec0 = ep[jn];
            ec1 = ep[(jn + 1 < dg) ? jn + 1 : jn];
            ra0 = *(const uint2*)(xlr2 + ((size_t)ec0.x << 6) + 4 * g);
            ra1 = *(const uint2*)(xlr2 + ((size_t)ec1.x << 6) + 4 * g);
        }
        float w0 = __int_as_float(c0.y), w1 = __int_as_float(c1.y);
        f32x2 ww0 = {w0, w0}, ww1 = {w1, w1};
        f32x2 a001 = b2x2(A0.x), a023 = b2x2(A0.y);
        f32x2 a101 = b2x2(A1.x), a123 = b2x2(A1.y);
        f32x2 p0v = {0.f, 0.f}, p1v = {0.f, 0.f}, z, lz;
        z = a001 + __builtin_elementwise_fma(ww0, we01, xr01);
        lz = __builtin_elementwise_max(z, z * NEG_SLOPE);
        p0v = __builtin_elementwise_fma(lz, at01, p0v);
        z = a023 + __builtin_elementwise_fma(ww0, we23, xr23);
        lz = __builtin_elementwise_max(z, z * NEG_SLOPE);
        p0v = __builtin_elementwise_fma(lz, at23, p0v);
        z = a101 + __builtin_elementwise_fma(ww1, we01, xr01);
        lz = __builtin_elementwise_max(z, z * NEG_SLOPE);
        p1v = __builtin_elementwise_fma(lz, at01, p1v);
        z = a123 + __builtin_elementwise_fma(ww1, we23, xr23);
        lz = __builtin_elementwise_max(z, z * NEG_SLOPE);
        p1v = __builtin_elementwise_fma(lz, at23, p1v);
        float p0 = p0v.x + p0v.y, p1 = p1v.x + p1v.y;
        p0 += __shfl_xor(p0, 1); p1 += __shfl_xor(p1, 1);
        p0 += __shfl_xor(p0, 2); p1 += __shfl_xor(p1, 2);
        p0 += __shfl_xor(p0, 4); p1 += __shfl_xor(p1, 4);
        if (j + 1 >= dg) p1 = -1e30f;
        float pm = fmaxf(p0, p1);
        if (__any(pm > m + RESCALE_THR2)) {
            float nm = fmaxf(m, pm);
            float sc = EXP2(m - nm);
            d *= sc;
            acc01 *= sc; acc23 *= sc;
            m = nm;
        }
        float e0 = EXP2(p0 - m), e1 = EXP2(p1 - m);
        d += e0 + e1;
        f32x2 ee0 = {e0, e0}, ee1 = {e1, e1};
        acc01 = __builtin_elementwise_fma(ee0, a001, acc01);
        acc23 = __builtin_elementwise_fma(ee0, a023, acc23);
        acc01 = __builtin_elementwise_fma(ee1, a101, acc01);
        acc23 = __builtin_elementwise_fma(ee1, a123, acc23);
    }
    float inv = 1.f / (d + 1e-16f);
    f32x2 b01 = ((const f32x2*)b2)[2 * g], b23 = ((const f32x2*)b2)[2 * g + 1];
    float vx = fmaxf(fmaf(acc01.x, inv, b01.x), 0.f);
    float vy = fmaxf(fmaf(acc01.y, inv, b01.y), 0.f);
    float vz = fmaxf(fmaf(acc23.x, inv, b23.x), 0.f);
    float vw = fmaxf(fmaf(acc23.y, inv, b23.y), 0.f);
    int b = batch[i];
    float* o = pool + (size_t)b * D_H + g * 4;
    atomicAdd(o + 0, vx);
    atomicAdd(o + 1, vy);
    atomicAdd(o + 2, vz);
    atomicAdd(o + 3, vw);
    if (g == 0) atomicAdd(&cnt[b], 1.0f);
}

// ---- mean, sigmoid, final FC ----
__global__ void k_final(const float* __restrict__ pool, const float* __restrict__ cnt,
                        const float* __restrict__ Wfc, const float* __restrict__ bfc,
                        float* __restrict__ out)
{
    int b = blockIdx.x * blockDim.x + threadIdx.x;
    if (b >= N_GRAPHS) return;
    float c = cnt[b]; c = c > 1.f ? c : 1.f;
    float acc = 0.f;
    #pragma unroll
    for (int j = 0; j < D_H; ++j) {
        float f = pool[b * D_H + j] / c;
        f = 1.f / (1.f + __expf(-f));
        acc = fmaf(f, Wfc[j], acc);
    }
    out[b] = acc + bfc[0];
}

extern "C" void kernel_launch(void* const* d_in, const int* in_sizes, int n_in,
                              void* d_out, int out_size, void* d_ws, size_t ws_size,
                              hipStream_t stream)
{
    const float* x    = (const float*)d_in[0];
    const int*   ei   = (const int*)  d_in[1];
    const int*   batch= (const int*)  d_in[2];
    const float* ew   = (const float*)d_in[3];
    const float* Wl1  = (const float*)d_in[4];
    const float* Wr1  = (const float*)d_in[5];
    const float* We1  = (const float*)d_in[6];
    const float* att1 = (const float*)d_in[7];
    const float* b1   = (const float*)d_in[8];
    const float* Wl2  = (const float*)d_in[9];
    const float* Wr2  = (const float*)d_in[10];
    const float* We2  = (const float*)d_in[11];
    const float* att2 = (const float*)d_in[12];
    const float* b2   = (const float*)d_in[13];
    const float* Wfc  = (const float*)d_in[14];
    const float* bfc  = (const float*)d_in[15];
    float* out = (float*)d_out;

    float* ws = (float*)d_ws;
    size_t off = 0;
    auto take = [&](size_t n) -> float* {
        float* p = ws + off;
        off = (off + n + 63) & ~(size_t)63;
        return p;
    };
    // --- zero-initialized region ---
    float* fillsum = take(1);
    int*   deg  = (int*)take(N_NODES);
    float* cnt  = take(N_GRAPHS);
    float* pool = take((size_t)N_GRAPHS * D_H);
    size_t zero_elems = off;
    // --- written-before-read buffers ---
    int*   start = (int*)take(N_NODES);
    int*   cur   = (int*)take(N_NODES);
    int*   bsum  = (int*)take(256);
    int2*  csr   = (int2*)take((size_t)E_TOT * 2);
    unsigned short* xb   = (unsigned short*)take((size_t)N_NODES * D_IN / 2);
    unsigned short* Wt1  = (unsigned short*)take(512 * 128 / 2);
    unsigned short* Wt2  = (unsigned short*)take(64 * 256 / 2);
    unsigned short* xlr1 = (unsigned short*)take((size_t)N_NODES * 512 / 2);
    unsigned short* out1 = (unsigned short*)take((size_t)N_NODES * 256 / 2);
    unsigned short* xlr2 = (unsigned short*)take((size_t)N_NODES * 64 / 2);
    (void)ws_size; (void)in_sizes; (void)n_in; (void)out_size;

    hipMemsetAsync(d_ws, 0, zero_elems * sizeof(float), stream);

    // fused front: fill-value sum + degree histogram + bf16 casts/panels
    k_front<<<RS_BLK + HIST_BLK + CAST_BLK + W1_BLK + W2_BLK, 256, 0, stream>>>(
        ew, ei, x, Wl1, Wr1, Wl2, Wr2, fillsum, deg, xb, Wt1, Wt2);

    k_scan1<<<NSCAN_BLK, 256, 0, stream>>>(deg, start, bsum);
    k_scan2<<<1, 256, 0, stream>>>(bsum, NSCAN_BLK);
    k_scan3<<<NSCAN_BLK, 256, 0, stream>>>(start, bsum, cur);
    k_scatter<<<(E_TOT + 255) / 256, 256, 0, stream>>>(ei, ew, fillsum, cur, csr);

    // layer-1 projection: xlr1 = xb @ [Wl1|Wr1]  (M=50000, N=512, K=128)
    k_gemm_bf16<128><<<dim3(512 / 64, (N_NODES + 63) / 64), 256, 0, stream>>>(
        xb, Wt1, xlr1, N_NODES, 512);

    // fused layer-1 edge phase
    k_gat1<<<(N_NODES * 64 + 255) / 256, 256, 0, stream>>>(
        xlr1, start, deg, csr, We1, att1, b1, out1);

    // layer-2 projection: xlr2 = out1 @ [Wl2|Wr2]  (M=50000, N=64, K=256)
    k_gemm_bf16<256><<<dim3(64 / 64, (N_NODES + 63) / 64), 256, 0, stream>>>(
        out1, Wt2, xlr2, N_NODES, 64);

    // fused layer-2 edge phase + pooling
    k_gat2<<<((size_t)N_NODES * 8 + 255) / 256, 256, 0, stream>>>(
        xlr2, start, deg, csr, We2, att2, b2, batch, pool, cnt);

    // final FC
    k_final<<<(N_GRAPHS + 255) / 256, 256, 0, stream>>>(pool, cnt, Wfc, bfc, out);
}

// Round 7
// 326.395 us; speedup vs baseline: 1.4456x; 1.0197x over previous
//
#include <hip/hip_runtime.h>
#include <math.h>

#define N_NODES 50000
#define N_EDGES 800000
#define D_IN    128
#define D_H     32
#define N_HEADS 8
#define N_GRAPHS 512
#define E_TOT   (N_EDGES + N_NODES)      // 850000 (with self-loops)
#define HDIM    (N_HEADS * D_H)          // 256
#define NEG_SLOPE 0.2f
#define NSCAN_BLK ((N_NODES + 255) / 256)   // 196
#define LOG2E 1.4426950408889634f
#define RESCALE_THR2 11.0f               // ~8 nats in log2 units

typedef short bfrag8 __attribute__((ext_vector_type(8)));   // 8 bf16 = 4 VGPRs
typedef float f32x4 __attribute__((ext_vector_type(4)));
typedef float f32x2 __attribute__((ext_vector_type(2)));

#if __has_builtin(__builtin_amdgcn_exp2f)
#define EXP2(x) __builtin_amdgcn_exp2f(x)
#else
#define EXP2(x) exp2f(x)
#endif

// ---- bf16 helpers ----
__device__ __forceinline__ unsigned short f2b(float x) {
    unsigned u = __float_as_uint(x);
    unsigned r = u + 0x7FFFu + ((u >> 16) & 1u);   // round-to-nearest-even
    return (unsigned short)(r >> 16);
}
// u32 holding two bf16 (lo=ch0, hi=ch1) -> f32x2 {ch0, ch1}
__device__ __forceinline__ f32x2 b2x2(unsigned u) {
    f32x2 v;
    v.x = __uint_as_float(u << 16);
    v.y = __uint_as_float(u & 0xFFFF0000u);
    return v;
}

// ---- 8-lane sum via DPP (VALU-only; replaces ds_swizzle shuffles) ----
// xor1 = quad_perm[1,0,3,2] (0xB1); xor2 = quad_perm[2,3,0,1] (0x4E);
// cross-quad within 8 = row_half_mirror (0x141) — valid because after the
// first two levels all lanes of a quad hold the same partial sum.
__device__ __forceinline__ float dpp8_sum(float x) {
    x += __int_as_float(__builtin_amdgcn_mov_dpp(__float_as_int(x), 0xB1, 0xF, 0xF, true));
    x += __int_as_float(__builtin_amdgcn_mov_dpp(__float_as_int(x), 0x4E, 0xF, 0xF, true));
    x += __int_as_float(__builtin_amdgcn_mov_dpp(__float_as_int(x), 0x141, 0xF, 0xF, true));
    return x;
}

// ==== fused front kernel: reduce_sum | hist | cast x | weight panels ====
#define RS_BLK   512
#define HIST_BLK ((E_TOT + 255) / 256)       // 3321
#define NC4      (N_NODES * D_IN / 4)        // 1,600,000 ushort4 casts
#define CAST_BLK ((NC4 + 255) / 256)         // 6250
#define W1_BLK   (512 * 128 / 256)           // 256
#define W2_BLK   (64 * 256 / 256)            // 64
__global__ void k_front(const float* __restrict__ ew, const int* __restrict__ ei,
                        const float* __restrict__ x,
                        const float* __restrict__ Wl1, const float* __restrict__ Wr1,
                        const float* __restrict__ Wl2, const float* __restrict__ Wr2,
                        float* __restrict__ fillsum, int* __restrict__ deg,
                        unsigned short* __restrict__ xb,
                        unsigned short* __restrict__ Wt1,
                        unsigned short* __restrict__ Wt2) {
    __shared__ float ls[4];
    int b = blockIdx.x;
    if (b < RS_BLK) {
        int t = b * 256 + threadIdx.x;
        float s = 0.f;
        for (int i = t; i < N_EDGES; i += RS_BLK * 256) s += ew[i];
        for (int m = 1; m < 64; m <<= 1) s += __shfl_xor(s, m);
        int lane = threadIdx.x & 63, wv = threadIdx.x >> 6;
        if (lane == 0) ls[wv] = s;
        __syncthreads();
        if (threadIdx.x == 0) atomicAdd(fillsum, ls[0] + ls[1] + ls[2] + ls[3]);
    } else if (b < RS_BLK + HIST_BLK) {
        int e = (b - RS_BLK) * 256 + threadIdx.x;
        if (e >= E_TOT) return;
        int dst = (e < N_EDGES) ? ei[N_EDGES + e] : (e - N_EDGES);
        atomicAdd(&deg[dst], 1);
    } else if (b < RS_BLK + HIST_BLK + CAST_BLK) {
        int t = (b - RS_BLK - HIST_BLK) * 256 + threadIdx.x;
        if (t >= NC4) return;
        float4 v = ((const float4*)x)[t];
        ushort4 o;
        o.x = f2b(v.x); o.y = f2b(v.y); o.z = f2b(v.z); o.w = f2b(v.w);
        ((ushort4*)xb)[t] = o;
    } else if (b < RS_BLK + HIST_BLK + CAST_BLK + W1_BLK) {
        int t = (b - RS_BLK - HIST_BLK - CAST_BLK) * 256 + threadIdx.x;  // c*128+k
        int c = t >> 7, k = t & 127;
        float v = (c < 256) ? Wl1[k * 256 + c] : Wr1[k * 256 + (c - 256)];
        Wt1[t] = f2b(v);
    } else {
        int t = (b - RS_BLK - HIST_BLK - CAST_BLK - W1_BLK) * 256 + threadIdx.x; // c*256+k
        int c = t >> 8, k = t & 255;
        float v = (c < 32) ? Wl2[k * 32 + c] : Wr2[k * 32 + (c - 32)];
        Wt2[t] = f2b(v);
    }
}

// ---- CSR scan (exclusive) ----
__global__ void k_scan1(const int* __restrict__ deg, int* __restrict__ start,
                        int* __restrict__ bsum) {
    __shared__ int sh[256];
    int i = blockIdx.x * 256 + threadIdx.x;
    int v = (i < N_NODES) ? deg[i] : 0;
    sh[threadIdx.x] = v;
    __syncthreads();
    for (int o = 1; o < 256; o <<= 1) {
        int t = (threadIdx.x >= o) ? sh[threadIdx.x - o] : 0;
        __syncthreads();
        sh[threadIdx.x] += t;
        __syncthreads();
    }
    if (i < N_NODES) start[i] = sh[threadIdx.x] - v;
    if (threadIdx.x == 255) bsum[blockIdx.x] = sh[255];
}
__global__ void k_scan2(int* __restrict__ bsum, int nb) {
    __shared__ int sh[256];
    int v = (threadIdx.x < nb) ? bsum[threadIdx.x] : 0;
    sh[threadIdx.x] = v;
    __syncthreads();
    for (int o = 1; o < 256; o <<= 1) {
        int t = (threadIdx.x >= o) ? sh[threadIdx.x - o] : 0;
        __syncthreads();
        sh[threadIdx.x] += t;
        __syncthreads();
    }
    if (threadIdx.x < nb) bsum[threadIdx.x] = sh[threadIdx.x] - v;
}
// also seeds cur[] = start[] so the scatter needs only one atomic per edge
__global__ void k_scan3(int* __restrict__ start, const int* __restrict__ bsum,
                        int* __restrict__ cur) {
    int i = blockIdx.x * 256 + threadIdx.x;
    if (i < N_NODES) {
        int v = start[i] + bsum[blockIdx.x];
        start[i] = v;
        cur[i] = v;
    }
}

// ---- CSR scatter: packed (src, w) int2 ----
__global__ void k_scatter(const int* __restrict__ ei, const float* __restrict__ ew,
                          const float* __restrict__ fillsum,
                          int* __restrict__ cur, int2* __restrict__ csr) {
    int e = blockIdx.x * blockDim.x + threadIdx.x;
    if (e >= E_TOT) return;
    int src, dst; float w;
    if (e < N_EDGES) { src = ei[e]; dst = ei[N_EDGES + e]; w = ew[e]; }
    else { src = dst = e - N_EDGES; w = fillsum[0] * (1.0f / N_EDGES); }
    int pos = atomicAdd(&cur[dst], 1);
    csr[pos] = make_int2(src, __float_as_int(w));
}

// ---- bf16 MFMA GEMM: C[M,N] = A[M,KC] * Bt[N,KC]^T, all bf16 row-major ----
template <int KC>
__global__ __launch_bounds__(256) void k_gemm_bf16(
    const unsigned short* __restrict__ A, const unsigned short* __restrict__ Bt,
    unsigned short* __restrict__ C, int M, int N)
{
    __shared__ unsigned short A_lds[64][KC + 8];
    __shared__ unsigned short B_lds[64][KC + 8];
    int row0 = blockIdx.y * 64, col0 = blockIdx.x * 64;
    int tid = threadIdx.x;
    const int CPR = KC / 8;
    for (int idx = tid; idx < 64 * CPR; idx += 256) {
        int r = idx / CPR, ch = idx % CPR;
        int gr = row0 + r;
        uint4 v = {0u, 0u, 0u, 0u};
        if (gr < M) v = *(const uint4*)(A + (size_t)gr * KC + ch * 8);
        *(uint4*)&A_lds[r][ch * 8] = v;
    }
    for (int idx = tid; idx < 64 * CPR; idx += 256) {
        int r = idx / CPR, ch = idx % CPR;
        uint4 v = *(const uint4*)(Bt + (size_t)(col0 + r) * KC + ch * 8);
        *(uint4*)&B_lds[r][ch * 8] = v;
    }
    __syncthreads();

    int wid = tid >> 6, lane = tid & 63;
    int wy = wid >> 1, wx = wid & 1;
    int lr = lane & 15, lh = lane >> 4;
    f32x4 acc[2][2] = {};
    #pragma unroll
    for (int k0 = 0; k0 < KC; k0 += 32) {
        bfrag8 a0 = *(const bfrag8*)&A_lds[32 * wy + lr][k0 + lh * 8];
        bfrag8 a1 = *(const bfrag8*)&A_lds[32 * wy + 16 + lr][k0 + lh * 8];
        bfrag8 b0 = *(const bfrag8*)&B_lds[32 * wx + lr][k0 + lh * 8];
        bfrag8 b1 = *(const bfrag8*)&B_lds[32 * wx + 16 + lr][k0 + lh * 8];
        acc[0][0] = __builtin_amdgcn_mfma_f32_16x16x32_bf16(a0, b0, acc[0][0], 0, 0, 0);
        acc[0][1] = __builtin_amdgcn_mfma_f32_16x16x32_bf16(a0, b1, acc[0][1], 0, 0, 0);
        acc[1][0] = __builtin_amdgcn_mfma_f32_16x16x32_bf16(a1, b0, acc[1][0], 0, 0, 0);
        acc[1][1] = __builtin_amdgcn_mfma_f32_16x16x32_bf16(a1, b1, acc[1][1], 0, 0, 0);
    }
    #pragma unroll
    for (int mt = 0; mt < 2; ++mt) {
        #pragma unroll
        for (int nt = 0; nt < 2; ++nt) {
            #pragma unroll
            for (int r = 0; r < 4; ++r) {
                int row = row0 + 32 * wy + 16 * mt + lh * 4 + r;
                if (row < M)
                    C[(size_t)row * N + col0 + 32 * wx + 16 * nt + lr] = f2b(acc[mt][nt][r]);
            }
        }
    }
}

// ---- fused layer-1: one wave per node; lane owns 4 of 256 channels ----
// 4-edge unroll, DPP reduce, packed f32x2 math, log2-space softmax.
__global__ __launch_bounds__(256, 8) void k_gat1(
    const unsigned short* __restrict__ xlr,
    const int* __restrict__ start, const int* __restrict__ deg,
    const int2* __restrict__ csr,
    const float* __restrict__ We, const float* __restrict__ att,
    const float* __restrict__ b1, unsigned short* __restrict__ out1)
{
    int wid = (blockIdx.x * blockDim.x + threadIdx.x) >> 6;
    int lane = threadIdx.x & 63;
    if (wid >= N_NODES) return;
    f32x2 we01 = ((const f32x2*)We)[2 * lane],  we23 = ((const f32x2*)We)[2 * lane + 1];
    f32x2 at01 = ((const f32x2*)att)[2 * lane], at23 = ((const f32x2*)att)[2 * lane + 1];
    at01 *= LOG2E; at23 *= LOG2E;               // fold ln->log2 into the dot
    uint2 xru = *(const uint2*)(xlr + (size_t)wid * 512 + 256 + 4 * lane);
    f32x2 xr01 = b2x2(xru.x), xr23 = b2x2(xru.y);
    int s0 = start[wid], dg = deg[wid];
    const int2* ep = csr + s0;
    float m = -1e30f, d = 0.f;
    f32x2 acc01 = {0.f, 0.f}, acc23 = {0.f, 0.f};

    // packed score in log2 space (conversions recomputed at accumulate)
    auto score = [&](uint2 A, float w) -> float {
        f32x2 ww = {w, w};
        f32x2 p = {0.f, 0.f}, z, lz;
        z = b2x2(A.x) + __builtin_elementwise_fma(ww, we01, xr01);
        lz = __builtin_elementwise_max(z, z * NEG_SLOPE);
        p = __builtin_elementwise_fma(lz, at01, p);
        z = b2x2(A.y) + __builtin_elementwise_fma(ww, we23, xr23);
        lz = __builtin_elementwise_max(z, z * NEG_SLOPE);
        p = __builtin_elementwise_fma(lz, at23, p);
        return p.x + p.y;
    };

    int dmax = dg - 1;
    int2 e0 = ep[0];
    int2 e1 = ep[1 < dmax ? 1 : dmax];
    int2 e2 = ep[2 < dmax ? 2 : dmax];
    int2 e3 = ep[3 < dmax ? 3 : dmax];
    uint2 r0 = *(const uint2*)(xlr + ((size_t)e0.x << 9) + 4 * lane);
    uint2 r1 = *(const uint2*)(xlr + ((size_t)e1.x << 9) + 4 * lane);
    uint2 r2 = *(const uint2*)(xlr + ((size_t)e2.x << 9) + 4 * lane);
    uint2 r3 = *(const uint2*)(xlr + ((size_t)e3.x << 9) + 4 * lane);

    for (int j = 0; j < dg; j += 4) {
        int2 c0 = e0, c1 = e1, c2 = e2, c3 = e3;
        uint2 A0 = r0, A1 = r1, A2 = r2, A3 = r3;
        int jn = j + 4;
        if (jn < dg) {
            e0 = ep[jn];
            e1 = ep[jn + 1 < dmax ? jn + 1 : dmax];
            e2 = ep[jn + 2 < dmax ? jn + 2 : dmax];
            e3 = ep[jn + 3 < dmax ? jn + 3 : dmax];
            r0 = *(const uint2*)(xlr + ((size_t)e0.x << 9) + 4 * lane);
            r1 = *(const uint2*)(xlr + ((size_t)e1.x << 9) + 4 * lane);
            r2 = *(const uint2*)(xlr + ((size_t)e2.x << 9) + 4 * lane);
            r3 = *(const uint2*)(xlr + ((size_t)e3.x << 9) + 4 * lane);
        }
        float w0 = __int_as_float(c0.y), w1 = __int_as_float(c1.y);
        float w2 = __int_as_float(c2.y), w3 = __int_as_float(c3.y);
        float p0 = score(A0, w0), p1 = score(A1, w1);
        float p2 = score(A2, w2), p3 = score(A3, w3);
        p0 = dpp8_sum(p0); p1 = dpp8_sum(p1);
        p2 = dpp8_sum(p2); p3 = dpp8_sum(p3);
        if (j + 1 >= dg) p1 = -1e30f;
        if (j + 2 >= dg) p2 = -1e30f;
        if (j + 3 >= dg) p3 = -1e30f;
        float pm = fmaxf(fmaxf(p0, p1), fmaxf(p2, p3));
        if (__any(pm > m + RESCALE_THR2)) {
            float nm = fmaxf(m, pm);
            float sc = EXP2(m - nm);
            d *= sc;
            acc01 *= sc; acc23 *= sc;
            m = nm;
        }
        float q0 = EXP2(p0 - m), q1 = EXP2(p1 - m);
        float q2 = EXP2(p2 - m), q3 = EXP2(p3 - m);
        d += (q0 + q1) + (q2 + q3);
        f32x2 qq;
        qq = (f32x2){q0, q0};
        acc01 = __builtin_elementwise_fma(qq, b2x2(A0.x), acc01);
        acc23 = __builtin_elementwise_fma(qq, b2x2(A0.y), acc23);
        qq = (f32x2){q1, q1};
        acc01 = __builtin_elementwise_fma(qq, b2x2(A1.x), acc01);
        acc23 = __builtin_elementwise_fma(qq, b2x2(A1.y), acc23);
        qq = (f32x2){q2, q2};
        acc01 = __builtin_elementwise_fma(qq, b2x2(A2.x), acc01);
        acc23 = __builtin_elementwise_fma(qq, b2x2(A2.y), acc23);
        qq = (f32x2){q3, q3};
        acc01 = __builtin_elementwise_fma(qq, b2x2(A3.x), acc01);
        acc23 = __builtin_elementwise_fma(qq, b2x2(A3.y), acc23);
    }
    float inv = 1.f / (d + 1e-16f);
    f32x2 b01 = ((const f32x2*)b1)[2 * lane], b23 = ((const f32x2*)b1)[2 * lane + 1];
    ushort4 o;
    o.x = f2b(fmaxf(fmaf(acc01.x, inv, b01.x), 0.f));
    o.y = f2b(fmaxf(fmaf(acc01.y, inv, b01.y), 0.f));
    o.z = f2b(fmaxf(fmaf(acc23.x, inv, b23.x), 0.f));
    o.w = f2b(fmaxf(fmaf(acc23.y, inv, b23.y), 0.f));
    *(ushort4*)(out1 + (size_t)wid * 256 + 4 * lane) = o;
}

// ---- fused layer-2 + pool: 8 threads per node; thread owns 4 of 32 channels ----
__global__ __launch_bounds__(256) void k_gat2(
    const unsigned short* __restrict__ xlr2,
    const int* __restrict__ start, const int* __restrict__ deg,
    const int2* __restrict__ csr,
    const float* __restrict__ We, const float* __restrict__ att,
    const float* __restrict__ b2, const int* __restrict__ batch,
    float* __restrict__ pool, float* __restrict__ cnt)
{
    int gt = blockIdx.x * blockDim.x + threadIdx.x;
    int i = gt >> 3, g = gt & 7;
    if (i >= N_NODES) return;
    f32x2 we01 = ((const f32x2*)We)[2 * g],  we23 = ((const f32x2*)We)[2 * g + 1];
    f32x2 at01 = ((const f32x2*)att)[2 * g], at23 = ((const f32x2*)att)[2 * g + 1];
    at01 *= LOG2E; at23 *= LOG2E;
    uint2 xru = *(const uint2*)(xlr2 + (size_t)i * 64 + 32 + 4 * g);
    f32x2 xr01 = b2x2(xru.x), xr23 = b2x2(xru.y);
    int s0 = start[i], dg = deg[i];
    const int2* ep = csr + s0;
    float m = -1e30f, d = 0.f;
    f32x2 acc01 = {0.f, 0.f}, acc23 = {0.f, 0.f};

    int2 ec0 = ep[0];
    int2 ec1 = ep[dg > 1 ? 1 : 0];
    uint2 ra0 = *(const uint2*)(xlr2 + ((size_t)ec0.x << 6) + 4 * g);
    uint2 ra1 = *(const uint2*)(xlr2 + ((size_t)ec1.x << 6) + 4 * g);

    for (int j = 0; j < dg; j += 2) {
        int2 c0 = ec0, c1 = ec1;
        uint2 A0 = ra0, A1 = ra1;
        int jn = j + 2;
        if (jn < dg) {
            ec0 = ep[jn];
            ec1 = ep[(jn + 1 < dg) ? jn + 1 : jn];
            ra0 = *(const uint2*)(xlr2 + ((size_t)ec0.x << 6) + 4 * g);
            ra1 = *(const uint2*)(xlr2 + ((size_t)ec1.x << 6) + 4 * g);
        }
        float w0 = __int_as_float(c0.y), w1 = __int_as_float(c1.y);
        f32x2 ww0 = {w0, w0}, ww1 = {w1, w1};
        f32x2 a001 = b2x2(A0.x), a023 = b2x2(A0.y);
        f32x2 a101 = b2x2(A1.x), a123 = b2x2(A1.y);
        f32x2 p0v = {0.f, 0.f}, p1v = {0.f, 0.f}, z, lz;
        z = a001 + __builtin_elementwise_fma(ww0, we01, xr01);
        lz = __builtin_elementwise_max(z, z * NEG_SLOPE);
        p0v = __builtin_elementwise_fma(lz, at01, p0v);
        z = a023 + __builtin_elementwise_fma(ww0, we23, xr23);
        lz = __builtin_elementwise_max(z, z * NEG_SLOPE);
        p0v = __builtin_elementwise_fma(lz, at23, p0v);
        z = a101 + __builtin_elementwise_fma(ww1, we01, xr01);
        lz = __builtin_elementwise_max(z, z * NEG_SLOPE);
        p1v = __builtin_elementwise_fma(lz, at01, p1v);
        z = a123 + __builtin_elementwise_fma(ww1, we23, xr23);
        lz = __builtin_elementwise_max(z, z * NEG_SLOPE);
        p1v = __builtin_elementwise_fma(lz, at23, p1v);
        float p0 = dpp8_sum(p0v.x + p0v.y);
        float p1 = dpp8_sum(p1v.x + p1v.y);
        if (j + 1 >= dg) p1 = -1e30f;
        float pm = fmaxf(p0, p1);
        if (__any(pm > m + RESCALE_THR2)) {
            float nm = fmaxf(m, pm);
            float sc = EXP2(m - nm);
            d *= sc;
            acc01 *= sc; acc23 *= sc;
            m = nm;
        }
        float q0 = EXP2(p0 - m), q1 = EXP2(p1 - m);
        d += q0 + q1;
        f32x2 qq0 = {q0, q0}, qq1 = {q1, q1};
        acc01 = __builtin_elementwise_fma(qq0, a001, acc01);
        acc23 = __builtin_elementwise_fma(qq0, a023, acc23);
        acc01 = __builtin_elementwise_fma(qq1, a101, acc01);
        acc23 = __builtin_elementwise_fma(qq1, a123, acc23);
    }
    float inv = 1.f / (d + 1e-16f);
    f32x2 b01 = ((const f32x2*)b2)[2 * g], b23 = ((const f32x2*)b2)[2 * g + 1];
    float vx = fmaxf(fmaf(acc01.x, inv, b01.x), 0.f);
    float vy = fmaxf(fmaf(acc01.y, inv, b01.y), 0.f);
    float vz = fmaxf(fmaf(acc23.x, inv, b23.x), 0.f);
    float vw = fmaxf(fmaf(acc23.y, inv, b23.y), 0.f);
    int b = batch[i];
    float* o = pool + (size_t)b * D_H + g * 4;
    atomicAdd(o + 0, vx);
    atomicAdd(o + 1, vy);
    atomicAdd(o + 2, vz);
    atomicAdd(o + 3, vw);
    if (g == 0) atomicAdd(&cnt[b], 1.0f);
}

// ---- mean, sigmoid, final FC ----
__global__ void k_final(const float* __restrict__ pool, const float* __restrict__ cnt,
                        const float* __restrict__ Wfc, const float* __restrict__ bfc,
                        float* __restrict__ out)
{
    int b = blockIdx.x * blockDim.x + threadIdx.x;
    if (b >= N_GRAPHS) return;
    float c = cnt[b]; c = c > 1.f ? c : 1.f;
    float acc = 0.f;
    #pragma unroll
    for (int j = 0; j < D_H; ++j) {
        float f = pool[b * D_H + j] / c;
        f = 1.f / (1.f + __expf(-f));
        acc = fmaf(f, Wfc[j], acc);
    }
    out[b] = acc + bfc[0];
}

extern "C" void kernel_launch(void* const* d_in, const int* in_sizes, int n_in,
                              void* d_out, int out_size, void* d_ws, size_t ws_size,
                              hipStream_t stream)
{
    const float* x    = (const float*)d_in[0];
    const int*   ei   = (const int*)  d_in[1];
    const int*   batch= (const int*)  d_in[2];
    const float* ew   = (const float*)d_in[3];
    const float* Wl1  = (const float*)d_in[4];
    const float* Wr1  = (const float*)d_in[5];
    const float* We1  = (const float*)d_in[6];
    const float* att1 = (const float*)d_in[7];
    const float* b1   = (const float*)d_in[8];
    const float* Wl2  = (const float*)d_in[9];
    const float* Wr2  = (const float*)d_in[10];
    const float* We2  = (const float*)d_in[11];
    const float* att2 = (const float*)d_in[12];
    const float* b2   = (const float*)d_in[13];
    const float* Wfc  = (const float*)d_in[14];
    const float* bfc  = (const float*)d_in[15];
    float* out = (float*)d_out;

    float* ws = (float*)d_ws;
    size_t off = 0;
    auto take = [&](size_t n) -> float* {
        float* p = ws + off;
        off = (off + n + 63) & ~(size_t)63;
        return p;
    };
    // --- zero-initialized region ---
    float* fillsum = take(1);
    int*   deg  = (int*)take(N_NODES);
    float* cnt  = take(N_GRAPHS);
    float* pool = take((size_t)N_GRAPHS * D_H);
    size_t zero_elems = off;
    // --- written-before-read buffers ---
    int*   start = (int*)take(N_NODES);
    int*   cur   = (int*)take(N_NODES);
    int*   bsum  = (int*)take(256);
    int2*  csr   = (int2*)take((size_t)E_TOT * 2);
    unsigned short* xb   = (unsigned short*)take((size_t)N_NODES * D_IN / 2);
    unsigned short* Wt1  = (unsigned short*)take(512 * 128 / 2);
    unsigned short* Wt2  = (unsigned short*)take(64 * 256 / 2);
    unsigned short* xlr1 = (unsigned short*)take((size_t)N_NODES * 512 / 2);
    unsigned short* out1 = (unsigned short*)take((size_t)N_NODES * 256 / 2);
    unsigned short* xlr2 = (unsigned short*)take((size_t)N_NODES * 64 / 2);
    (void)ws_size; (void)in_sizes; (void)n_in; (void)out_size;

    hipMemsetAsync(d_ws, 0, zero_elems * sizeof(float), stream);

    // fused front: fill-value sum + degree histogram + bf16 casts/panels
    k_front<<<RS_BLK + HIST_BLK + CAST_BLK + W1_BLK + W2_BLK, 256, 0, stream>>>(
        ew, ei, x, Wl1, Wr1, Wl2, Wr2, fillsum, deg, xb, Wt1, Wt2);

    k_scan1<<<NSCAN_BLK, 256, 0, stream>>>(deg, start, bsum);
    k_scan2<<<1, 256, 0, stream>>>(bsum, NSCAN_BLK);
    k_scan3<<<NSCAN_BLK, 256, 0, stream>>>(start, bsum, cur);
    k_scatter<<<(E_TOT + 255) / 256, 256, 0, stream>>>(ei, ew, fillsum, cur, csr);

    // layer-1 projection: xlr1 = xb @ [Wl1|Wr1]  (M=50000, N=512, K=128)
    k_gemm_bf16<128><<<dim3(512 / 64, (N_NODES + 63) / 64), 256, 0, stream>>>(
        xb, Wt1, xlr1, N_NODES, 512);

    // fused layer-1 edge phase
    k_gat1<<<(N_NODES * 64 + 255) / 256, 256, 0, stream>>>(
        xlr1, start, deg, csr, We1, att1, b1, out1);

    // layer-2 projection: xlr2 = out1 @ [Wl2|Wr2]  (M=50000, N=64, K=256)
    k_gemm_bf16<256><<<dim3(64 / 64, (N_NODES + 63) / 64), 256, 0, stream>>>(
        out1, Wt2, xlr2, N_NODES, 64);

    // fused layer-2 edge phase + pooling
    k_gat2<<<((size_t)N_NODES * 8 + 255) / 256, 256, 0, stream>>>(
        xlr2, start, deg, csr, We2, att2, b2, batch, pool, cnt);

    // final FC
    k_final<<<(N_GRAPHS + 255) / 256, 256, 0, stream>>>(pool, cnt, Wfc, bfc, out);
}